// Round 5
// baseline (201.375 us; speedup 1.0000x reference)
//
#include <hip/hip_runtime.h>
#include <hip/hip_cooperative_groups.h>
#include <stdint.h>
#include <stddef.h>

namespace cg = cooperative_groups;

// ---------------------------------------------------------------------------
// ModuleGARO: corr(256x256 per bt, 512 bt) -> [512,65536]@[65536,256] GEMM ->
// BN/ReLU chain -> sigmoid QK attention scale.
// Linear biases before BN cancel exactly (x - mu), so m1b/m2b/p1b/p2b dropped.
// Tail (stats+3 GEMMs+qk+att) = ONE cooperative kernel, MFMA bf16, grid syncs.
// ws layout (bytes):
//   WT    bf16 256x65536    33,554,432
//   fc    bf16 512x65536    67,108,864
//   P     f32  64x512x256   33,554,432
//   z1    f32  512x256         524,288
//   WTs   bf16 {m2,p1,p2,k}^T  655,360
//   pSQ   float2[4][64][256]   524,288
//   pH    f32 [64][256]         65,536
//   qv    f32 [8][256]           8,192
// ---------------------------------------------------------------------------

typedef short short8 __attribute__((ext_vector_type(8)));
typedef float f32x4 __attribute__((ext_vector_type(4)));

#define DEV __device__ __forceinline__

DEV unsigned short f2bf(float f){
  union { float f; unsigned u; } v; v.f = f;
  unsigned r = v.u + 0x7FFFu + ((v.u >> 16) & 1u);   // RNE
  return (unsigned short)(r >> 16);
}
DEV float bf2f(unsigned short b){
  union { unsigned u; float f; } v; v.u = ((unsigned)b) << 16;
  return v.f;
}
DEV void gload_lds16(const void* g, void* l){
  __builtin_amdgcn_global_load_lds(
      (const __attribute__((address_space(1))) unsigned int*)g,
      (__attribute__((address_space(3))) unsigned int*)l, 16, 0, 0);
}

// ---------------------------------------------------------------------------
// k_wt: WT[o][k] = bf16(m1W[k][o]); 64x64 tiles via LDS transpose.
// ---------------------------------------------------------------------------
__global__ __launch_bounds__(256) void k_wt(const float* __restrict__ W,
                                            unsigned short* __restrict__ WT){
  __shared__ float tile[64][65];
  const int k0 = blockIdx.x * 64;
  const int o0 = blockIdx.y * 64;
  const int tr = threadIdx.x >> 6;   // 0..3
  const int tc = threadIdx.x & 63;
  #pragma unroll
  for (int i = 0; i < 16; ++i){
    int kr = i*4 + tr;
    tile[kr][tc] = W[(size_t)(k0+kr)*256 + o0 + tc];
  }
  __syncthreads();
  #pragma unroll
  for (int i = 0; i < 16; ++i){
    int orow = i*4 + tr;
    WT[(size_t)(o0+orow)*65536 + k0 + tc] = f2bf(tile[tc][orow]);
  }
}

// ---------------------------------------------------------------------------
// k_wts: transpose+bf16 the 4 small tail weights into WTs:
//   m2WT [256][256] @0, p1WT [256][512] @65536, p2WT [256][256] @196608,
//   kWT  [256][256] @262144.  grid (20 ktiles, 4 otiles).
// ---------------------------------------------------------------------------
__global__ __launch_bounds__(256) void k_wts(const float* __restrict__ m2W,
                                             const float* __restrict__ p1W,
                                             const float* __restrict__ p2W,
                                             const float* __restrict__ kW,
                                             unsigned short* __restrict__ WTs){
  __shared__ float tile[64][65];
  const int bx = blockIdx.x;
  const float* W; int K; size_t dst; int kt;
  if (bx < 4)       { W = m2W; K = 256; dst = 0;      kt = bx; }
  else if (bx < 12) { W = p1W; K = 512; dst = 65536;  kt = bx - 4; }
  else if (bx < 16) { W = p2W; K = 256; dst = 196608; kt = bx - 12; }
  else              { W = kW;  K = 256; dst = 262144; kt = bx - 16; }
  const int k0 = kt*64, o0 = blockIdx.y*64;
  const int tr = threadIdx.x >> 6, tc = threadIdx.x & 63;
  #pragma unroll
  for (int i = 0; i < 16; ++i){
    int kr = i*4 + tr;
    tile[kr][tc] = W[(size_t)(k0+kr)*256 + o0 + tc];
  }
  __syncthreads();
  #pragma unroll
  for (int i = 0; i < 16; ++i){
    int orow = i*4 + tr;
    WTs[dst + (size_t)(o0+orow)*K + k0 + tc] = f2bf(tile[tc][orow]);
  }
}

// ---------------------------------------------------------------------------
// k_corr: one block per bt. corr = (y^T y) * rs_i * rs_j, clip [-1,1], bf16.
// ---------------------------------------------------------------------------
__global__ __launch_bounds__(256) void k_corr(const float* __restrict__ x,
                                              unsigned short* __restrict__ fc){
  __shared__ unsigned short yT[256*72];
  __shared__ float rs[256];
  __shared__ unsigned short stg[4][64*40];
  const int bt = blockIdx.x;
  const float* xb = x + (size_t)bt * 16384;   // 64 samples x 256 vars
  const int i = threadIdx.x;                  // column (variable) index

  float sum = 0.f;
  #pragma unroll 8
  for (int s = 0; s < 64; ++s) sum += xb[s*256 + i];
  const float mean = sum * (1.f/64.f);

  float ss = 0.f;
  unsigned int* yT32 = (unsigned int*)yT;
  #pragma unroll 4
  for (int s = 0; s < 64; s += 2){
    float v0 = xb[s*256 + i] - mean;
    float v1 = xb[(s+1)*256 + i] - mean;
    unsigned short b0 = f2bf(v0), b1 = f2bf(v1);
    float r0 = bf2f(b0), r1 = bf2f(b1);
    ss += r0*r0 + r1*r1;                      // sumsq of the *rounded* values
    yT32[(i*72 + s) >> 1] = (unsigned)b0 | ((unsigned)b1 << 16);
  }
  rs[i] = rsqrtf(ss);
  __syncthreads();

  const int w   = threadIdx.x >> 6;           // wave 0..3 -> rows w*64..w*64+63
  const int l   = threadIdx.x & 63;
  const int l15 = l & 15, lg = l >> 4;

  short8 RF[4][2];
  #pragma unroll
  for (int rt = 0; rt < 4; ++rt){
    int row = w*64 + rt*16 + l15;
    #pragma unroll
    for (int ks = 0; ks < 2; ++ks)
      RF[rt][ks] = *(const short8*)&yT[row*72 + ks*32 + lg*8];
  }
  float rrow[4][4];
  #pragma unroll
  for (int rt = 0; rt < 4; ++rt)
    #pragma unroll
    for (int r = 0; r < 4; ++r)
      rrow[rt][r] = rs[w*64 + rt*16 + lg*4 + r];

  unsigned short* sg = stg[w];
  for (int cc = 0; cc < 8; ++cc){             // 8 chunks of 32 output cols
    short8 CF[2][2];
    #pragma unroll
    for (int ct = 0; ct < 2; ++ct){
      int col = cc*32 + ct*16 + l15;
      #pragma unroll
      for (int ks = 0; ks < 2; ++ks)
        CF[ct][ks] = *(const short8*)&yT[col*72 + ks*32 + lg*8];
    }
    f32x4 acc[4][2];
    #pragma unroll
    for (int rt = 0; rt < 4; ++rt)
      #pragma unroll
      for (int ct = 0; ct < 2; ++ct)
        acc[rt][ct] = (f32x4){0.f,0.f,0.f,0.f};
    #pragma unroll
    for (int ks = 0; ks < 2; ++ks)
      #pragma unroll
      for (int rt = 0; rt < 4; ++rt)
        #pragma unroll
        for (int ct = 0; ct < 2; ++ct)
          acc[rt][ct] = __builtin_amdgcn_mfma_f32_16x16x32_bf16(
              RF[rt][ks], CF[ct][ks], acc[rt][ct], 0, 0, 0);

    float rc[2] = { rs[cc*32 + l15], rs[cc*32 + 16 + l15] };
    #pragma unroll
    for (int rt = 0; rt < 4; ++rt)
      #pragma unroll
      for (int ct = 0; ct < 2; ++ct)
        #pragma unroll
        for (int r = 0; r < 4; ++r){
          float v = acc[rt][ct][r] * rrow[rt][r] * rc[ct];
          v = fminf(fmaxf(v, -1.f), 1.f);
          sg[(rt*16 + lg*4 + r)*40 + ct*16 + l15] = f2bf(v);
        }
    #pragma unroll
    for (int idx = 0; idx < 4; ++idx){
      int c = idx*64 + l;
      int rowL = c >> 2, ch = c & 3;
      short8 v = *(const short8*)&sg[rowL*40 + ch*8];
      *(short8*)&fc[(size_t)bt*65536 + (size_t)(w*64 + rowL)*256 + cc*32 + ch*8] = v;
    }
  }
}

// ---------------------------------------------------------------------------
// k_gemm: [512,65536]bf16 @ WT^T -> split-K fp32 partials (no bias).
// BM=128, BN=256, BK=64, 512 thr / 8 waves, 2-phase dbuf LDS.
// ---------------------------------------------------------------------------
__global__ __launch_bounds__(512) void k_gemm(const unsigned short* __restrict__ fc,
                                              const unsigned short* __restrict__ WT,
                                              float* __restrict__ P){
  __shared__ unsigned short Al[2][128*64];
  __shared__ unsigned short Bl[2][256*64];
  const int ksb = blockIdx.x;
  const int m0  = blockIdx.y * 128;
  const int k0  = ksb * 1024;
  const int t   = threadIdx.x;
  const int w = t >> 6, l = t & 63, l15 = l & 15, lg = l >> 4;
  const int wr = (w >> 2) * 64;     // 0,64
  const int wc = (w & 3) * 64;      // 0..192

  auto stage = [&](int b, int kt){
    const int kk = k0 + kt*64;
    #pragma unroll
    for (int i = 0; i < 2; ++i){
      int c = i*512 + t;
      int row = c >> 3, ch = c & 7;
      int sch = ch ^ (row & 7);
      gload_lds16(fc + (size_t)(m0+row)*65536 + kk + sch*8, &Al[b][c*8]);
    }
    #pragma unroll
    for (int i = 0; i < 4; ++i){
      int c = i*512 + t;
      int row = c >> 3, ch = c & 7;
      int sch = ch ^ (row & 7);
      gload_lds16(WT + (size_t)row*65536 + kk + sch*8, &Bl[b][c*8]);
    }
  };

  f32x4 acc[4][4];
  #pragma unroll
  for (int a = 0; a < 4; ++a)
    #pragma unroll
    for (int b = 0; b < 4; ++b) acc[a][b] = (f32x4){0.f,0.f,0.f,0.f};

  stage(0, 0);
  int cur = 0;
  for (int kt = 0; kt < 16; ++kt){
    __syncthreads();                 // buf[cur] staged; prev buf reads done
    if (kt < 15) stage(cur ^ 1, kt + 1);
    #pragma unroll
    for (int ks = 0; ks < 2; ++ks){
      short8 af[4], bf[4];
      #pragma unroll
      for (int rt = 0; rt < 4; ++rt){
        int row = wr + rt*16 + l15;
        int pch = (ks*4 + lg) ^ (row & 7);
        af[rt] = *(const short8*)&Al[cur][row*64 + pch*8];
      }
      #pragma unroll
      for (int ct = 0; ct < 4; ++ct){
        int row = wc + ct*16 + l15;
        int pch = (ks*4 + lg) ^ (row & 7);
        bf[ct] = *(const short8*)&Bl[cur][row*64 + pch*8];
      }
      #pragma unroll
      for (int rt = 0; rt < 4; ++rt)
        #pragma unroll
        for (int ct = 0; ct < 4; ++ct)
          acc[rt][ct] = __builtin_amdgcn_mfma_f32_16x16x32_bf16(
              af[rt], bf[ct], acc[rt][ct], 0, 0, 0);
    }
    cur ^= 1;
  }

  float* Pb = P + (size_t)ksb * 131072;
  #pragma unroll
  for (int rt = 0; rt < 4; ++rt)
    #pragma unroll
    for (int ct = 0; ct < 4; ++ct)
      #pragma unroll
      for (int r = 0; r < 4; ++r){
        int row = m0 + wr + rt*16 + lg*4 + r;
        int col = wc + ct*16 + l15;
        Pb[(size_t)row*256 + col] = acc[rt][ct][r];
      }
}

// ---------------------------------------------------------------------------
// k_reduce: z[row][j] = sum_ks P[ks][row][j]. 256 blocks x 2 rows, float2.
// ---------------------------------------------------------------------------
__global__ __launch_bounds__(256) void k_reduce(const float* __restrict__ P,
                                                float* __restrict__ z){
  const int row = blockIdx.x*2 + (threadIdx.x >> 7);
  const int c2  = (threadIdx.x & 127) * 2;
  float sx = 0.f, sy = 0.f;
  #pragma unroll 8
  for (int ks = 0; ks < 64; ++ks){
    const float* p = &P[(size_t)ks*131072 + row*256 + c2];
    sx += p[0]; sy += p[1];
  }
  z[row*256 + c2]     = sx;
  z[row*256 + c2 + 1] = sy;
}

// ---------------------------------------------------------------------------
// k_tail: ONE cooperative kernel for the whole tail. 64 blocks x 8 rows.
// phases (separated by grid.sync):
//  ph0: stats1 partials from z1        -> pS0
//  ph1: ss1; xbf=relu(bn1(z1)); MFMA m2 -> acc; stats2 partials -> pS1
//  ph2: ss2; xbf<-acc; +es; MFMA p1(K=512) -> acc; stats3 -> pS2
//  ph3: ss3; xbf<-acc; MFMA p2 -> acc; stats4 -> pS3
//  ph4: ss4; Hh,xbf<-acc; qmean partials -> pH
//  ph5: blocks<8: hm; q = hm@qW + qb -> qv
//  ph6: MFMA kW -> z5; s=dot(q,z5+kb)/16; out = Hh*sigmoid(s)
// ---------------------------------------------------------------------------
__global__ __launch_bounds__(256) void k_tail(
    const float* __restrict__ z1, const float* __restrict__ e_s,
    const unsigned short* __restrict__ m2WT, const unsigned short* __restrict__ p1WT,
    const unsigned short* __restrict__ p2WT, const unsigned short* __restrict__ kWT,
    const float* __restrict__ m1g, const float* __restrict__ m1be,
    const float* __restrict__ m2g, const float* __restrict__ m2be,
    const float* __restrict__ p1g, const float* __restrict__ p1be,
    const float* __restrict__ p2g, const float* __restrict__ p2be,
    const float* __restrict__ qW, const float* __restrict__ qb,
    const float* __restrict__ kb,
    float2* __restrict__ pSQ, float* __restrict__ pH,
    float* __restrict__ qv, float* __restrict__ out)
{
  cg::grid_group grid = cg::this_grid();
  __shared__ unsigned short xbf[16][528];   // A operand, bf16 (rows 8..15 = 0)
  __shared__ float Hh[8][256];
  __shared__ float2 ssl[256];
  __shared__ float pr[4][16];
  __shared__ float sig[16];
  __shared__ float hm[256];

  const int bid = blockIdx.x;          // 64 blocks, 8 rows each
  const int t = threadIdx.x;
  const int r0 = bid*8, b = bid >> 3;
  const int w = t >> 6, l = t & 63, l15 = l & 15, lg = l >> 4;
  const int wc = w*64;
  float2* pS0 = pSQ;
  float2* pS1 = pSQ + 16384;
  float2* pS2 = pSQ + 32768;
  float2* pS3 = pSQ + 49152;

  // zero the pad rows (8..15) of xbf once
  for (int r = 8; r < 16; ++r)
    for (int c = t; c < 528; c += 256) xbf[r][c] = 0;

  // ph0: stats1 partials over our 8 rows of z1
  {
    float S = 0.f, Q = 0.f;
    #pragma unroll
    for (int r = 0; r < 8; ++r){ float v = z1[(r0+r)*256 + t]; S += v; Q += v*v; }
    pS0[bid*256 + t] = make_float2(S, Q);
  }
  grid.sync();

  // combine partials -> ssl[t] = {sc, sh}
  auto combine_ss = [&](const float2* pS, const float* g, const float* be){
    float S = 0.f, Q = 0.f;
    #pragma unroll 8
    for (int i = 0; i < 64; ++i){ float2 p = pS[i*256 + t]; S += p.x; Q += p.y; }
    float mu  = S * (1.f/512.f);
    float var = Q * (1.f/512.f) - mu*mu;
    float sc = g[t] * rsqrtf(var + 1e-5f);
    ssl[t] = make_float2(sc, be[t] - mu*sc);
  };

  // MFMA layer: acc[ct] (+= over K) = xbf(16 x K) @ WT(256 x K)^T, wave cols wc..wc+63
  auto layer = [&](const unsigned short* WT, int K, f32x4* acc){
    #pragma unroll
    for (int ct = 0; ct < 4; ++ct) acc[ct] = (f32x4){0.f,0.f,0.f,0.f};
    for (int ks = 0; ks < K/32; ++ks){
      short8 af = *(const short8*)&xbf[l15][ks*32 + lg*8];
      #pragma unroll
      for (int ct = 0; ct < 4; ++ct){
        short8 bf = *(const short8*)&WT[(size_t)(wc + ct*16 + l15)*K + ks*32 + lg*8];
        acc[ct] = __builtin_amdgcn_mfma_f32_16x16x32_bf16(af, bf, acc[ct], 0, 0, 0);
      }
    }
  };

  // per-column partial S,Q from acc (pad rows contribute 0)
  auto stats_partial = [&](f32x4* acc, float2* dst){
    #pragma unroll
    for (int ct = 0; ct < 4; ++ct){
      float S = acc[ct][0] + acc[ct][1] + acc[ct][2] + acc[ct][3];
      float Q = acc[ct][0]*acc[ct][0] + acc[ct][1]*acc[ct][1]
              + acc[ct][2]*acc[ct][2] + acc[ct][3]*acc[ct][3];
      S += __shfl_xor(S, 16); S += __shfl_xor(S, 32);
      Q += __shfl_xor(Q, 16); Q += __shfl_xor(Q, 32);
      if (lg == 0) dst[bid*256 + wc + ct*16 + l15] = make_float2(S, Q);
    }
  };

  // acc -> xbf (BN+ReLU, bf16); real rows only
  auto acc_to_xbf = [&](f32x4* acc){
    #pragma unroll
    for (int ct = 0; ct < 4; ++ct){
      int col = wc + ct*16 + l15;
      float2 sv = ssl[col];
      #pragma unroll
      for (int r = 0; r < 4; ++r){
        int row = lg*4 + r;
        if (row < 8){
          float v = fmaxf(acc[ct][r]*sv.x + sv.y, 0.f);
          xbf[row][col] = f2bf(v);
        }
      }
    }
  };

  f32x4 acc[4];

  // ph1: ss1 -> xbf from z1 -> layer m2 -> stats2
  combine_ss(pS0, m1g, m1be);
  {
    float2 sv = ssl[t];
    #pragma unroll
    for (int r = 0; r < 8; ++r)
      xbf[r][t] = f2bf(fmaxf(z1[(r0+r)*256 + t]*sv.x + sv.y, 0.f));
  }
  __syncthreads();
  layer(m2WT, 256, acc);
  stats_partial(acc, pS1);
  grid.sync();

  // ph2: ss2 -> xbf from acc; es concat; layer p1 (K=512) -> stats3
  combine_ss(pS1, m2g, m2be);
  __syncthreads();               // ssl ready for all cols
  acc_to_xbf(acc);
  {
    unsigned short ebf = f2bf(e_s[b*256 + t]);
    #pragma unroll
    for (int r = 0; r < 8; ++r) xbf[r][256 + t] = ebf;
  }
  __syncthreads();
  layer(p1WT, 512, acc);
  stats_partial(acc, pS2);
  grid.sync();

  // ph3: ss3 -> xbf from acc; layer p2 -> stats4
  combine_ss(pS2, p1g, p1be);
  __syncthreads();
  acc_to_xbf(acc);
  __syncthreads();
  layer(p2WT, 256, acc);
  stats_partial(acc, pS3);
  grid.sync();

  // ph4: ss4 -> Hh (f32) + xbf (bf16); qmean partials
  combine_ss(pS3, p2g, p2be);
  __syncthreads();
  #pragma unroll
  for (int ct = 0; ct < 4; ++ct){
    int col = wc + ct*16 + l15;
    float2 sv = ssl[col];
    #pragma unroll
    for (int r = 0; r < 4; ++r){
      int row = lg*4 + r;
      if (row < 8){
        float v = fmaxf(acc[ct][r]*sv.x + sv.y, 0.f);
        Hh[row][col] = v;
        xbf[row][col] = f2bf(v);
      }
    }
  }
  __syncthreads();
  {
    float S = 0.f;
    #pragma unroll
    for (int r = 0; r < 8; ++r) S += Hh[r][t];
    pH[bid*256 + t] = S;
  }
  grid.sync();

  // ph5: blocks 0..7 compute q[b] = (mean_t Hh) @ qW + qb
  if (bid < 8){
    float S = 0.f;
    #pragma unroll
    for (int i = 0; i < 8; ++i) S += pH[(bid*8 + i)*256 + t];
    hm[t] = S * (1.f/64.f);
    __syncthreads();
    float a = 0.f;
    #pragma unroll 8
    for (int k = 0; k < 256; ++k) a += hm[k] * qW[k*256 + t];
    qv[bid*256 + t] = a + qb[t];
  }
  grid.sync();

  // ph6: kvec = Hh @ kW + kb; s = dot(q_b, kvec)/16; out = Hh * sigmoid(s)
  layer(kWT, 256, acc);
  {
    const float* qb_ = qv + b*256;
    float p[4] = {0.f, 0.f, 0.f, 0.f};
    #pragma unroll
    for (int ct = 0; ct < 4; ++ct){
      int col = wc + ct*16 + l15;
      float qc = qb_[col];
      float kbc = kb[col];
      #pragma unroll
      for (int r = 0; r < 4; ++r) p[r] += (acc[ct][r] + kbc) * qc;
    }
    #pragma unroll
    for (int r = 0; r < 4; ++r){
      p[r] += __shfl_xor(p[r], 1);
      p[r] += __shfl_xor(p[r], 2);
      p[r] += __shfl_xor(p[r], 4);
      p[r] += __shfl_xor(p[r], 8);
    }
    if (l15 == 0){
      #pragma unroll
      for (int r = 0; r < 4; ++r){
        int row = lg*4 + r;
        if (row < 8) pr[w][row] = p[r];
      }
    }
    __syncthreads();
    if (t < 8){
      float s = pr[0][t] + pr[1][t] + pr[2][t] + pr[3][t];
      sig[t] = 1.f / (1.f + __expf(-s * (1.f/16.f)));
    }
    __syncthreads();
    #pragma unroll
    for (int r = 0; r < 8; ++r)
      out[(r0+r)*256 + t] = Hh[r][t] * sig[r];
  }
}

// ---------------------------------------------------------------------------
extern "C" void kernel_launch(void* const* d_in, const int* in_sizes, int n_in,
                              void* d_out, int out_size, void* d_ws, size_t ws_size,
                              hipStream_t stream){
  (void)in_sizes; (void)n_in; (void)out_size; (void)ws_size;
  const float* x    = (const float*)d_in[0];
  const float* e_s  = (const float*)d_in[1];
  const float* qW   = (const float*)d_in[2];
  const float* qb   = (const float*)d_in[3];
  const float* kW   = (const float*)d_in[4];
  const float* kb   = (const float*)d_in[5];
  const float* m1W  = (const float*)d_in[6];
  const float* m1g  = (const float*)d_in[8];
  const float* m1be = (const float*)d_in[9];
  const float* m2W  = (const float*)d_in[10];
  const float* m2g  = (const float*)d_in[12];
  const float* m2be = (const float*)d_in[13];
  const float* p1W  = (const float*)d_in[14];
  const float* p1g  = (const float*)d_in[16];
  const float* p1be = (const float*)d_in[17];
  const float* p2W  = (const float*)d_in[18];
  const float* p2g  = (const float*)d_in[20];
  const float* p2be = (const float*)d_in[21];
  // biases m1b,m2b,p1b,p2b (d_in[7,11,15,19]) cancel in BN — unused.

  char* ws = (char*)d_ws;
  unsigned short* WT  = (unsigned short*)ws; ws += 33554432;
  unsigned short* fc  = (unsigned short*)ws; ws += 67108864;
  float* P            = (float*)ws;  ws += 33554432;
  float* z1           = (float*)ws;  ws += 524288;
  unsigned short* WTs = (unsigned short*)ws; ws += 655360;
  float2* pSQ         = (float2*)ws; ws += 524288;
  float* pH           = (float*)ws;  ws += 65536;
  float* qvv          = (float*)ws;  ws += 8192;
  float* outp = (float*)d_out;

  const unsigned short* m2WT = WTs;
  const unsigned short* p1WT = WTs + 65536;
  const unsigned short* p2WT = WTs + 196608;
  const unsigned short* kWT  = WTs + 262144;

  k_wt    <<<dim3(1024, 4), 256, 0, stream>>>(m1W, WT);
  k_wts   <<<dim3(20, 4), 256, 0, stream>>>(m2W, p1W, p2W, kW, (unsigned short*)WTs);
  k_corr  <<<512, 256, 0, stream>>>(x, fc);
  k_gemm  <<<dim3(64, 4), 512, 0, stream>>>(fc, WT, P);
  k_reduce<<<256, 256, 0, stream>>>(P, z1);

  void* args[] = {
    (void*)&z1, (void*)&e_s, (void*)&m2WT, (void*)&p1WT, (void*)&p2WT, (void*)&kWT,
    (void*)&m1g, (void*)&m1be, (void*)&m2g, (void*)&m2be,
    (void*)&p1g, (void*)&p1be, (void*)&p2g, (void*)&p2be,
    (void*)&qW, (void*)&qb, (void*)&kb,
    (void*)&pSQ, (void*)&pH, (void*)&qvv, (void*)&outp
  };
  hipLaunchCooperativeKernel((const void*)k_tail, dim3(64), dim3(256),
                             args, 0, stream);
}

// Round 6
// 143.509 us; speedup vs baseline: 1.4032x; 1.4032x over previous
//
#include <hip/hip_runtime.h>
#include <stdint.h>
#include <stddef.h>

// ---------------------------------------------------------------------------
// ModuleGARO: corr(256x256 per bt, 512 bt) -> [512,65536]@[65536,256] GEMM ->
// BN/ReLU chain -> sigmoid QK attention scale.
// Linear biases before BN cancel exactly (x - mu), so m1b/m2b/p1b/p2b dropped.
// R6: tail reverted to R4 multi-kernel (R5 cooperative tail was latency-bound:
// 103us, occ 2.8%). k_gemm redesigned: BM=64,BN=128, 24KB LDS, 1024 blocks =
// 4 blocks/CU for cross-block overlap (m97 mechanism), XCD-chunk swizzle.
// k_wt + k_corr merged into k_prep (one launch, shared smem arena).
// ws: WT 33.5MB | fc 67MB | P 33.5MB | z1..z4 | s1..s4 | qv
// ---------------------------------------------------------------------------

typedef short short8 __attribute__((ext_vector_type(8)));
typedef float f32x4 __attribute__((ext_vector_type(4)));

#define DEV __device__ __forceinline__

DEV unsigned short f2bf(float f){
  union { float f; unsigned u; } v; v.f = f;
  unsigned r = v.u + 0x7FFFu + ((v.u >> 16) & 1u);   // RNE
  return (unsigned short)(r >> 16);
}
DEV float bf2f(unsigned short b){
  union { unsigned u; float f; } v; v.u = ((unsigned)b) << 16;
  return v.f;
}
DEV void gload_lds16(const void* g, void* l){
  __builtin_amdgcn_global_load_lds(
      (const __attribute__((address_space(1))) unsigned int*)g,
      (__attribute__((address_space(3))) unsigned int*)l, 16, 0, 0);
}

// ---------------------------------------------------------------------------
// k_prep: blocks [0,512) = corr (one block per bt); blocks [512,4608) = wt
// transpose (m1W f32 [65536][256] -> WT bf16 [256][65536]).
// Shared 58,368B arena: corr{yT 36864 | rs 1024 | stg 20480}; wt{tile 16640}.
// ---------------------------------------------------------------------------
__global__ __launch_bounds__(256) void k_prep(const float* __restrict__ x,
                                              unsigned short* __restrict__ fc,
                                              const float* __restrict__ W,
                                              unsigned short* __restrict__ WT){
  __shared__ __align__(16) char smem[58368];

  if (blockIdx.x >= 512){
    // ---- wt: 64x64 tile transpose+cast ----
    float (*tile)[65] = (float(*)[65])smem;
    const int bid2 = blockIdx.x - 512;
    const int k0 = (bid2 >> 2) * 64;
    const int o0 = (bid2 & 3) * 64;
    const int tr = threadIdx.x >> 6;
    const int tc = threadIdx.x & 63;
    #pragma unroll
    for (int i = 0; i < 16; ++i){
      int kr = i*4 + tr;
      tile[kr][tc] = W[(size_t)(k0+kr)*256 + o0 + tc];
    }
    __syncthreads();
    #pragma unroll
    for (int i = 0; i < 16; ++i){
      int orow = i*4 + tr;
      WT[(size_t)(o0+orow)*65536 + k0 + tc] = f2bf(tile[tc][orow]);
    }
    return;
  }

  // ---- corr: corr = (y^T y) * rs_i * rs_j, clip [-1,1], bf16 ----
  unsigned short* yT  = (unsigned short*)smem;            // 256*72 u16
  float*          rs  = (float*)(smem + 36864);           // 256 f32
  unsigned short* stg = (unsigned short*)(smem + 37888);  // 4*64*40 u16
  const int bt = blockIdx.x;
  const float* xb = x + (size_t)bt * 16384;   // 64 samples x 256 vars
  const int i = threadIdx.x;

  float sum = 0.f;
  #pragma unroll 8
  for (int s = 0; s < 64; ++s) sum += xb[s*256 + i];
  const float mean = sum * (1.f/64.f);

  float ss = 0.f;
  unsigned int* yT32 = (unsigned int*)yT;
  #pragma unroll 4
  for (int s = 0; s < 64; s += 2){
    float v0 = xb[s*256 + i] - mean;
    float v1 = xb[(s+1)*256 + i] - mean;
    unsigned short b0 = f2bf(v0), b1 = f2bf(v1);
    float r0 = bf2f(b0), r1 = bf2f(b1);
    ss += r0*r0 + r1*r1;                      // sumsq of the *rounded* values
    yT32[(i*72 + s) >> 1] = (unsigned)b0 | ((unsigned)b1 << 16);
  }
  rs[i] = rsqrtf(ss);
  __syncthreads();

  const int w   = threadIdx.x >> 6;           // wave 0..3 -> rows w*64..+63
  const int l   = threadIdx.x & 63;
  const int l15 = l & 15, lg = l >> 4;

  short8 RF[4][2];
  #pragma unroll
  for (int rt = 0; rt < 4; ++rt){
    int row = w*64 + rt*16 + l15;
    #pragma unroll
    for (int ks = 0; ks < 2; ++ks)
      RF[rt][ks] = *(const short8*)&yT[row*72 + ks*32 + lg*8];
  }
  float rrow[4][4];
  #pragma unroll
  for (int rt = 0; rt < 4; ++rt)
    #pragma unroll
    for (int r = 0; r < 4; ++r)
      rrow[rt][r] = rs[w*64 + rt*16 + lg*4 + r];

  unsigned short* sg = stg + w*2560;
  for (int cc = 0; cc < 8; ++cc){
    short8 CF[2][2];
    #pragma unroll
    for (int ct = 0; ct < 2; ++ct){
      int col = cc*32 + ct*16 + l15;
      #pragma unroll
      for (int ks = 0; ks < 2; ++ks)
        CF[ct][ks] = *(const short8*)&yT[col*72 + ks*32 + lg*8];
    }
    f32x4 acc[4][2];
    #pragma unroll
    for (int rt = 0; rt < 4; ++rt)
      #pragma unroll
      for (int ct = 0; ct < 2; ++ct)
        acc[rt][ct] = (f32x4){0.f,0.f,0.f,0.f};
    #pragma unroll
    for (int ks = 0; ks < 2; ++ks)
      #pragma unroll
      for (int rt = 0; rt < 4; ++rt)
        #pragma unroll
        for (int ct = 0; ct < 2; ++ct)
          acc[rt][ct] = __builtin_amdgcn_mfma_f32_16x16x32_bf16(
              RF[rt][ks], CF[ct][ks], acc[rt][ct], 0, 0, 0);

    float rc[2] = { rs[cc*32 + l15], rs[cc*32 + 16 + l15] };
    #pragma unroll
    for (int rt = 0; rt < 4; ++rt)
      #pragma unroll
      for (int ct = 0; ct < 2; ++ct)
        #pragma unroll
        for (int r = 0; r < 4; ++r){
          float v = acc[rt][ct][r] * rrow[rt][r] * rc[ct];
          v = fminf(fmaxf(v, -1.f), 1.f);
          sg[(rt*16 + lg*4 + r)*40 + ct*16 + l15] = f2bf(v);
        }
    #pragma unroll
    for (int idx = 0; idx < 4; ++idx){
      int c = idx*64 + l;
      int rowL = c >> 2, ch = c & 3;
      short8 v = *(const short8*)&sg[rowL*40 + ch*8];
      *(short8*)&fc[(size_t)bt*65536 + (size_t)(w*64 + rowL)*256 + cc*32 + ch*8] = v;
    }
  }
}

// ---------------------------------------------------------------------------
// k_gemm: [512,65536]bf16 @ WT^T -> split-K fp32 partials (no bias).
// BM=64, BN=128, BK=64, 256 thr / 4 waves (wave tile 32x64), 24KB LDS
// single-buffered m97-style loop; grid 1024 1D = 4 blocks/CU; XCD-chunk
// swizzle: wgid = (bid%8)*128 + bid/8 -> per-XCD 128-block chunk shares
// 8 ksb x 2 n B-slices (4MB = one XCD L2).
// ---------------------------------------------------------------------------
__global__ __launch_bounds__(256) void k_gemm(const unsigned short* __restrict__ fc,
                                              const unsigned short* __restrict__ WT,
                                              float* __restrict__ P){
  __shared__ unsigned short Al[64*64];
  __shared__ unsigned short Bl[128*64];
  const int bid  = blockIdx.x;
  const int wgid = (bid & 7)*128 + (bid >> 3);  // bijective (1024 % 8 == 0)
  const int ksb  = wgid >> 4;
  const int rem  = wgid & 15;
  const int n0   = (rem >> 3) * 128;
  const int m0   = (rem & 7) * 64;
  const int k0   = ksb * 1024;
  const int t    = threadIdx.x;
  const int w = t >> 6, l = t & 63, l15 = l & 15, lg = l >> 4;
  const int wr = (w >> 1) * 32;   // 0,32
  const int wc = (w & 1) * 64;    // 0,64

  f32x4 acc[2][4];
  #pragma unroll
  for (int a = 0; a < 2; ++a)
    #pragma unroll
    for (int b = 0; b < 4; ++b) acc[a][b] = (f32x4){0.f,0.f,0.f,0.f};

  for (int kt = 0; kt < 16; ++kt){
    const int kk = k0 + kt*64;
    #pragma unroll
    for (int i = 0; i < 2; ++i){           // A: 64 rows x 64 k
      int c = i*256 + t;
      int row = c >> 3, ch = c & 7;
      int sch = ch ^ (row & 7);
      gload_lds16(fc + (size_t)(m0+row)*65536 + kk + sch*8, &Al[c*8]);
    }
    #pragma unroll
    for (int i = 0; i < 4; ++i){           // B: 128 rows x 64 k
      int c = i*256 + t;
      int row = c >> 3, ch = c & 7;
      int sch = ch ^ (row & 7);
      gload_lds16(WT + (size_t)(n0+row)*65536 + kk + sch*8, &Bl[c*8]);
    }
    __syncthreads();
    #pragma unroll
    for (int ks = 0; ks < 2; ++ks){
      short8 af[2], bf[4];
      #pragma unroll
      for (int rt = 0; rt < 2; ++rt){
        int row = wr + rt*16 + l15;
        int pch = (ks*4 + lg) ^ (row & 7);
        af[rt] = *(const short8*)&Al[row*64 + pch*8];
      }
      #pragma unroll
      for (int ct = 0; ct < 4; ++ct){
        int row = wc + ct*16 + l15;
        int pch = (ks*4 + lg) ^ (row & 7);
        bf[ct] = *(const short8*)&Bl[row*64 + pch*8];
      }
      #pragma unroll
      for (int rt = 0; rt < 2; ++rt)
        #pragma unroll
        for (int ct = 0; ct < 4; ++ct)
          acc[rt][ct] = __builtin_amdgcn_mfma_f32_16x16x32_bf16(
              af[rt], bf[ct], acc[rt][ct], 0, 0, 0);
    }
    __syncthreads();
  }

  float* Pb = P + (size_t)ksb * 131072;
  #pragma unroll
  for (int rt = 0; rt < 2; ++rt)
    #pragma unroll
    for (int ct = 0; ct < 4; ++ct)
      #pragma unroll
      for (int r = 0; r < 4; ++r){
        int row = m0 + wr + rt*16 + lg*4 + r;
        int col = n0 + wc + ct*16 + l15;
        Pb[(size_t)row*256 + col] = acc[rt][ct][r];
      }
}

// ---------------------------------------------------------------------------
// k_reduce: z[row][j] = sum_ks P[ks][row][j]. 256 blocks x 2 rows, float2.
// ---------------------------------------------------------------------------
__global__ __launch_bounds__(256) void k_reduce(const float* __restrict__ P,
                                                float* __restrict__ z){
  const int row = blockIdx.x*2 + (threadIdx.x >> 7);
  const int c2  = (threadIdx.x & 127) * 2;
  float sx = 0.f, sy = 0.f;
  #pragma unroll 8
  for (int ks = 0; ks < 64; ++ks){
    const float* p = &P[(size_t)ks*131072 + row*256 + c2];
    sx += p[0]; sy += p[1];
  }
  z[row*256 + c2]     = sx;
  z[row*256 + c2 + 1] = sy;
}

// ---------------------------------------------------------------------------
// k_stats: per-column batch stats over 512 rows (biased var) ->
// ss[j] = {sc, sh} with sc = g*rsqrt(var+eps), sh = beta - mu*sc.
// ---------------------------------------------------------------------------
__global__ __launch_bounds__(256) void k_stats(const float* __restrict__ z,
                                               const float* __restrict__ g,
                                               const float* __restrict__ beta,
                                               float2* __restrict__ ss){
  const int j = blockIdx.x, t = threadIdx.x;
  float v0 = z[t*256 + j], v1 = z[(t+256)*256 + j];
  float s = v0 + v1, q = v0*v0 + v1*v1;
  #pragma unroll
  for (int o = 1; o < 64; o <<= 1){ s += __shfl_xor(s, o); q += __shfl_xor(q, o); }
  __shared__ float sw[4], qw[4];
  if ((t & 63) == 0){ sw[t >> 6] = s; qw[t >> 6] = q; }
  __syncthreads();
  if (t == 0){
    float S = sw[0] + sw[1] + sw[2] + sw[3];
    float Q = qw[0] + qw[1] + qw[2] + qw[3];
    float mu  = S * (1.f/512.f);
    float var = Q * (1.f/512.f) - mu*mu;
    float sc = g[j] * rsqrtf(var + 1e-5f);
    ss[j] = make_float2(sc, beta[j] - mu*sc);
  }
}

// ---------------------------------------------------------------------------
// k_sg: z_out = [relu(bn(z_in)) | es?] @ W  (no bias; BN applied inline).
// W staged in double-buffered LDS chunks. Block = 2 bt rows; thread = col.
// ---------------------------------------------------------------------------
template<int KK, bool CAT>
__global__ __launch_bounds__(256) void k_sg(const float* __restrict__ zin,
                                            const float2* __restrict__ ss,
                                            const float* __restrict__ es,
                                            const float* __restrict__ W,
                                            float* __restrict__ zout){
  __shared__ float Wl[2][64*256];   // 128 KB double-buffered K-chunks
  __shared__ float xr[2][KK];
  const int bt0 = blockIdx.x * 2;
  const int t = threadIdx.x;
  float2 sv = ss[t];
  xr[0][t] = fmaxf(zin[bt0*256 + t]*sv.x + sv.y, 0.f);
  xr[1][t] = fmaxf(zin[(bt0+1)*256 + t]*sv.x + sv.y, 0.f);
  if constexpr (CAT){
    float e = es[(bt0 >> 6)*256 + t];
    xr[0][256 + t] = e;
    xr[1][256 + t] = e;
  }
  auto stage = [&](int b, int c0){
    const float* Wg = W + (size_t)c0 * 64 * 256;
    #pragma unroll
    for (int i = 0; i < 16; ++i){
      int c = i*256 + t;
      gload_lds16(Wg + c*4, &Wl[b][c*4]);
    }
  };
  constexpr int NC = KK / 64;
  stage(0, 0);
  float a0 = 0.f, a1 = 0.f;
  int cur = 0;
  for (int c = 0; c < NC; ++c){
    __syncthreads();
    if (c + 1 < NC) stage(cur ^ 1, c + 1);
    #pragma unroll 16
    for (int k = 0; k < 64; ++k){
      float wv = Wl[cur][k*256 + t];
      a0 += xr[0][c*64 + k] * wv;
      a1 += xr[1][c*64 + k] * wv;
    }
    cur ^= 1;
  }
  zout[bt0*256 + t]     = a0;
  zout[(bt0+1)*256 + t] = a1;
}

// ---------------------------------------------------------------------------
// k_qmean: per b: hm = mean_t relu(bn4(z4[b,t,:])); q = hm @ qW + qb.
// ---------------------------------------------------------------------------
__global__ __launch_bounds__(256) void k_qmean(const float* __restrict__ z4,
                                               const float2* __restrict__ ss,
                                               const float* __restrict__ qW,
                                               const float* __restrict__ qb,
                                               float* __restrict__ q){
  __shared__ float Wl[2][64*256];
  __shared__ float hm[256];
  const int b = blockIdx.x, t = threadIdx.x;
  float2 sv = ss[t];
  float s = 0.f;
  #pragma unroll 8
  for (int tt = 0; tt < 64; ++tt)
    s += fmaxf(z4[((b<<6)+tt)*256 + t]*sv.x + sv.y, 0.f);
  hm[t] = s * (1.f/64.f);
  auto stage = [&](int bb, int c0){
    const float* Wg = qW + (size_t)c0 * 64 * 256;
    #pragma unroll
    for (int i = 0; i < 16; ++i){
      int c = i*256 + t;
      gload_lds16(Wg + c*4, &Wl[bb][c*4]);
    }
  };
  stage(0, 0);
  float a = 0.f;
  int cur = 0;
  for (int c = 0; c < 4; ++c){
    __syncthreads();
    if (c < 3) stage(cur ^ 1, c + 1);
    #pragma unroll 16
    for (int k = 0; k < 64; ++k)
      a += hm[c*64 + k] * Wl[cur][k*256 + t];
    cur ^= 1;
  }
  q[b*256 + t] = a + qb[t];
}

// ---------------------------------------------------------------------------
// k_att: per 2 bt rows: Hh = relu(bn4(z4)); kvec = Hh @ kW + kb;
//        s = dot(q_b, kvec)/16; out = Hh * sigmoid(s). grid 256 blocks.
// ---------------------------------------------------------------------------
__global__ __launch_bounds__(256) void k_att(const float* __restrict__ z4,
                                             const float2* __restrict__ ss,
                                             const float* __restrict__ kW,
                                             const float* __restrict__ kb,
                                             const float* __restrict__ q,
                                             float* __restrict__ out){
  __shared__ float Wl[2][64*256];
  __shared__ float xr[2][256];
  __shared__ float pw[2][4];
  const int bt0 = blockIdx.x * 2;
  const int b = bt0 >> 6;
  const int t = threadIdx.x;
  float2 sv = ss[t];
  xr[0][t] = fmaxf(z4[bt0*256 + t]*sv.x + sv.y, 0.f);
  xr[1][t] = fmaxf(z4[(bt0+1)*256 + t]*sv.x + sv.y, 0.f);
  auto stage = [&](int bb, int c0){
    const float* Wg = kW + (size_t)c0 * 64 * 256;
    #pragma unroll
    for (int i = 0; i < 16; ++i){
      int c = i*256 + t;
      gload_lds16(Wg + c*4, &Wl[bb][c*4]);
    }
  };
  stage(0, 0);
  float a0 = 0.f, a1 = 0.f;
  int cur = 0;
  for (int c = 0; c < 4; ++c){
    __syncthreads();
    if (c < 3) stage(cur ^ 1, c + 1);
    #pragma unroll 16
    for (int k = 0; k < 64; ++k){
      float wv = Wl[cur][k*256 + t];
      a0 += xr[0][c*64 + k] * wv;
      a1 += xr[1][c*64 + k] * wv;
    }
    cur ^= 1;
  }
  float qv = q[b*256 + t];
  float p0 = (a0 + kb[t]) * qv;
  float p1 = (a1 + kb[t]) * qv;
  #pragma unroll
  for (int o = 1; o < 64; o <<= 1){
    p0 += __shfl_xor(p0, o);
    p1 += __shfl_xor(p1, o);
  }
  if ((t & 63) == 0){ pw[0][t >> 6] = p0; pw[1][t >> 6] = p1; }
  __syncthreads();
  float s0 = (pw[0][0] + pw[0][1] + pw[0][2] + pw[0][3]) * (1.f/16.f);
  float s1 = (pw[1][0] + pw[1][1] + pw[1][2] + pw[1][3]) * (1.f/16.f);
  float g0 = 1.f / (1.f + __expf(-s0));
  float g1 = 1.f / (1.f + __expf(-s1));
  out[bt0*256 + t]     = xr[0][t] * g0;
  out[(bt0+1)*256 + t] = xr[1][t] * g1;
}

// ---------------------------------------------------------------------------
extern "C" void kernel_launch(void* const* d_in, const int* in_sizes, int n_in,
                              void* d_out, int out_size, void* d_ws, size_t ws_size,
                              hipStream_t stream){
  (void)in_sizes; (void)n_in; (void)out_size; (void)ws_size;
  const float* x    = (const float*)d_in[0];
  const float* e_s  = (const float*)d_in[1];
  const float* qW   = (const float*)d_in[2];
  const float* qb   = (const float*)d_in[3];
  const float* kW   = (const float*)d_in[4];
  const float* kb   = (const float*)d_in[5];
  const float* m1W  = (const float*)d_in[6];
  const float* m1g  = (const float*)d_in[8];
  const float* m1be = (const float*)d_in[9];
  const float* m2W  = (const float*)d_in[10];
  const float* m2g  = (const float*)d_in[12];
  const float* m2be = (const float*)d_in[13];
  const float* p1W  = (const float*)d_in[14];
  const float* p1g  = (const float*)d_in[16];
  const float* p1be = (const float*)d_in[17];
  const float* p2W  = (const float*)d_in[18];
  const float* p2g  = (const float*)d_in[20];
  const float* p2be = (const float*)d_in[21];
  // biases m1b,m2b,p1b,p2b (d_in[7,11,15,19]) cancel in BN — unused.

  char* ws = (char*)d_ws;
  unsigned short* WT = (unsigned short*)ws; ws += 33554432;
  unsigned short* fc = (unsigned short*)ws; ws += 67108864;
  float* P   = (float*)ws;  ws += 33554432;
  float* z1  = (float*)ws;  ws += 524288;
  float* z2  = (float*)ws;  ws += 524288;
  float* z3  = (float*)ws;  ws += 524288;
  float* z4  = (float*)ws;  ws += 524288;
  float2* s1 = (float2*)ws; ws += 2048;
  float2* s2 = (float2*)ws; ws += 2048;
  float2* s3 = (float2*)ws; ws += 2048;
  float2* s4 = (float2*)ws; ws += 2048;
  float* qv  = (float*)ws;  ws += 8192;
  float* out = (float*)d_out;

  k_prep  <<<4608, 256, 0, stream>>>(x, fc, m1W, WT);   // corr (512) + wt (4096)
  k_gemm  <<<1024, 256, 0, stream>>>(fc, WT, P);
  k_reduce<<<256, 256, 0, stream>>>(P, z1);
  k_stats <<<256, 256, 0, stream>>>(z1, m1g, m1be, s1);
  k_sg<256,false><<<256, 256, 0, stream>>>(z1, s1, nullptr, m2W, z2);
  k_stats <<<256, 256, 0, stream>>>(z2, m2g, m2be, s2);
  k_sg<512,true> <<<256, 256, 0, stream>>>(z2, s2, e_s, p1W, z3);
  k_stats <<<256, 256, 0, stream>>>(z3, p1g, p1be, s3);
  k_sg<256,false><<<256, 256, 0, stream>>>(z3, s3, nullptr, p2W, z4);
  k_stats <<<256, 256, 0, stream>>>(z4, p2g, p2be, s4);
  k_qmean <<<8, 256, 0, stream>>>(z4, s4, qW, qb, qv);
  k_att   <<<256, 256, 0, stream>>>(z4, s4, kW, kb, qv, out);
}

// Round 7
// 142.906 us; speedup vs baseline: 1.4091x; 1.0042x over previous
//
#include <hip/hip_runtime.h>
#include <stdint.h>
#include <stddef.h>

// ---------------------------------------------------------------------------
// ModuleGARO: corr(256x256 per bt, 512 bt) -> [512,65536]@[65536,256] GEMM ->
// BN/ReLU chain -> sigmoid QK attention scale.
// Linear biases before BN cancel exactly (x - mu) -> m1b/m2b/p1b/p2b dropped.
// R7: prep un-merged (R6 merge: 58KB arena killed transpose occupancy ->
// 2TB/s). Tail rebuilt as MFMA weight-stationary kernels (32 blocks x 16
// rows, full W^T in 128KB LDS, BN stats fused via atomicAdd partials).
// ws: WT 33.5MB | fc 67MB | P 33.5MB | z1..z4 | WTs 640KB | SQ | qv
// ---------------------------------------------------------------------------

typedef short short8 __attribute__((ext_vector_type(8)));
typedef float f32x4 __attribute__((ext_vector_type(4)));

#define DEV __device__ __forceinline__

DEV unsigned short f2bf(float f){
  union { float f; unsigned u; } v; v.f = f;
  unsigned r = v.u + 0x7FFFu + ((v.u >> 16) & 1u);   // RNE
  return (unsigned short)(r >> 16);
}
DEV float bf2f(unsigned short b){
  union { unsigned u; float f; } v; v.u = ((unsigned)b) << 16;
  return v.f;
}
DEV void gload_lds16(const void* g, void* l){
  __builtin_amdgcn_global_load_lds(
      (const __attribute__((address_space(1))) unsigned int*)g,
      (__attribute__((address_space(3))) unsigned int*)l, 16, 0, 0);
}

// ---------------------------------------------------------------------------
// k_wt: WT[o][k] = bf16(m1W[k][o]); 64x64 tiles via LDS transpose. (R4 form)
// ---------------------------------------------------------------------------
__global__ __launch_bounds__(256) void k_wt(const float* __restrict__ W,
                                            unsigned short* __restrict__ WT){
  __shared__ float tile[64][65];
  const int k0 = blockIdx.x * 64;
  const int o0 = blockIdx.y * 64;
  const int tr = threadIdx.x >> 6;   // 0..3
  const int tc = threadIdx.x & 63;
  #pragma unroll
  for (int i = 0; i < 16; ++i){
    int kr = i*4 + tr;
    tile[kr][tc] = W[(size_t)(k0+kr)*256 + o0 + tc];
  }
  __syncthreads();
  #pragma unroll
  for (int i = 0; i < 16; ++i){
    int orow = i*4 + tr;
    WT[(size_t)(o0+orow)*65536 + k0 + tc] = f2bf(tile[tc][orow]);
  }
}

// ---------------------------------------------------------------------------
// k_wts: transpose+bf16 the 4 tail weights into WTs (R5-verified) + zero SQ.
//   m2WT [256][256] @0, p1WT [256][512] @65536, p2WT [256][256] @196608,
//   kWT  [256][256] @262144.  grid (20 ktiles, 4 otiles).
// ---------------------------------------------------------------------------
__global__ __launch_bounds__(256) void k_wts(const float* __restrict__ m2W,
                                             const float* __restrict__ p1W,
                                             const float* __restrict__ p2W,
                                             const float* __restrict__ kW,
                                             unsigned short* __restrict__ WTs,
                                             float2* __restrict__ SQ){
  if (blockIdx.x == 0 && blockIdx.y == 0){
    for (int i = threadIdx.x; i < 1024; i += 256) SQ[i] = make_float2(0.f, 0.f);
  }
  __shared__ float tile[64][65];
  const int bx = blockIdx.x;
  const float* W; int K; size_t dst; int kt;
  if (bx < 4)       { W = m2W; K = 256; dst = 0;      kt = bx; }
  else if (bx < 12) { W = p1W; K = 512; dst = 65536;  kt = bx - 4; }
  else if (bx < 16) { W = p2W; K = 256; dst = 196608; kt = bx - 12; }
  else              { W = kW;  K = 256; dst = 262144; kt = bx - 16; }
  const int k0 = kt*64, o0 = blockIdx.y*64;
  const int tr = threadIdx.x >> 6, tc = threadIdx.x & 63;
  #pragma unroll
  for (int i = 0; i < 16; ++i){
    int kr = i*4 + tr;
    tile[kr][tc] = W[(size_t)(k0+kr)*256 + o0 + tc];
  }
  __syncthreads();
  #pragma unroll
  for (int i = 0; i < 16; ++i){
    int orow = i*4 + tr;
    WTs[dst + (size_t)(o0+orow)*K + k0 + tc] = f2bf(tile[tc][orow]);
  }
}

// ---------------------------------------------------------------------------
// k_corr: one block per bt. corr = (y^T y) * rs_i * rs_j, clip, bf16. (R4)
// ---------------------------------------------------------------------------
__global__ __launch_bounds__(256) void k_corr(const float* __restrict__ x,
                                              unsigned short* __restrict__ fc){
  __shared__ unsigned short yT[256*72];
  __shared__ float rs[256];
  __shared__ unsigned short stg[4][64*40];
  const int bt = blockIdx.x;
  const float* xb = x + (size_t)bt * 16384;   // 64 samples x 256 vars
  const int i = threadIdx.x;

  float sum = 0.f;
  #pragma unroll 8
  for (int s = 0; s < 64; ++s) sum += xb[s*256 + i];
  const float mean = sum * (1.f/64.f);

  float ss = 0.f;
  unsigned int* yT32 = (unsigned int*)yT;
  #pragma unroll 4
  for (int s = 0; s < 64; s += 2){
    float v0 = xb[s*256 + i] - mean;
    float v1 = xb[(s+1)*256 + i] - mean;
    unsigned short b0 = f2bf(v0), b1 = f2bf(v1);
    float r0 = bf2f(b0), r1 = bf2f(b1);
    ss += r0*r0 + r1*r1;
    yT32[(i*72 + s) >> 1] = (unsigned)b0 | ((unsigned)b1 << 16);
  }
  rs[i] = rsqrtf(ss);
  __syncthreads();

  const int w   = threadIdx.x >> 6;
  const int l   = threadIdx.x & 63;
  const int l15 = l & 15, lg = l >> 4;

  short8 RF[4][2];
  #pragma unroll
  for (int rt = 0; rt < 4; ++rt){
    int row = w*64 + rt*16 + l15;
    #pragma unroll
    for (int ks = 0; ks < 2; ++ks)
      RF[rt][ks] = *(const short8*)&yT[row*72 + ks*32 + lg*8];
  }
  float rrow[4][4];
  #pragma unroll
  for (int rt = 0; rt < 4; ++rt)
    #pragma unroll
    for (int r = 0; r < 4; ++r)
      rrow[rt][r] = rs[w*64 + rt*16 + lg*4 + r];

  unsigned short* sg = stg[w];
  for (int cc = 0; cc < 8; ++cc){
    short8 CF[2][2];
    #pragma unroll
    for (int ct = 0; ct < 2; ++ct){
      int col = cc*32 + ct*16 + l15;
      #pragma unroll
      for (int ks = 0; ks < 2; ++ks)
        CF[ct][ks] = *(const short8*)&yT[col*72 + ks*32 + lg*8];
    }
    f32x4 acc[4][2];
    #pragma unroll
    for (int rt = 0; rt < 4; ++rt)
      #pragma unroll
      for (int ct = 0; ct < 2; ++ct)
        acc[rt][ct] = (f32x4){0.f,0.f,0.f,0.f};
    #pragma unroll
    for (int ks = 0; ks < 2; ++ks)
      #pragma unroll
      for (int rt = 0; rt < 4; ++rt)
        #pragma unroll
        for (int ct = 0; ct < 2; ++ct)
          acc[rt][ct] = __builtin_amdgcn_mfma_f32_16x16x32_bf16(
              RF[rt][ks], CF[ct][ks], acc[rt][ct], 0, 0, 0);

    float rc[2] = { rs[cc*32 + l15], rs[cc*32 + 16 + l15] };
    #pragma unroll
    for (int rt = 0; rt < 4; ++rt)
      #pragma unroll
      for (int ct = 0; ct < 2; ++ct)
        #pragma unroll
        for (int r = 0; r < 4; ++r){
          float v = acc[rt][ct][r] * rrow[rt][r] * rc[ct];
          v = fminf(fmaxf(v, -1.f), 1.f);
          sg[(rt*16 + lg*4 + r)*40 + ct*16 + l15] = f2bf(v);
        }
    #pragma unroll
    for (int idx = 0; idx < 4; ++idx){
      int c = idx*64 + l;
      int rowL = c >> 2, ch = c & 3;
      short8 v = *(const short8*)&sg[rowL*40 + ch*8];
      *(short8*)&fc[(size_t)bt*65536 + (size_t)(w*64 + rowL)*256 + cc*32 + ch*8] = v;
    }
  }
}

// ---------------------------------------------------------------------------
// k_gemm: [512,65536]bf16 @ WT^T -> split-K fp32 partials. (R6 form)
// BM=64, BN=128, BK=64, 4 blocks/CU, XCD-chunk swizzle.
// ---------------------------------------------------------------------------
__global__ __launch_bounds__(256) void k_gemm(const unsigned short* __restrict__ fc,
                                              const unsigned short* __restrict__ WT,
                                              float* __restrict__ P){
  __shared__ unsigned short Al[64*64];
  __shared__ unsigned short Bl[128*64];
  const int bid  = blockIdx.x;
  const int wgid = (bid & 7)*128 + (bid >> 3);
  const int ksb  = wgid >> 4;
  const int rem  = wgid & 15;
  const int n0   = (rem >> 3) * 128;
  const int m0   = (rem & 7) * 64;
  const int k0   = ksb * 1024;
  const int t    = threadIdx.x;
  const int w = t >> 6, l = t & 63, l15 = l & 15, lg = l >> 4;
  const int wr = (w >> 1) * 32;
  const int wc = (w & 1) * 64;

  f32x4 acc[2][4];
  #pragma unroll
  for (int a = 0; a < 2; ++a)
    #pragma unroll
    for (int b = 0; b < 4; ++b) acc[a][b] = (f32x4){0.f,0.f,0.f,0.f};

  for (int kt = 0; kt < 16; ++kt){
    const int kk = k0 + kt*64;
    #pragma unroll
    for (int i = 0; i < 2; ++i){
      int c = i*256 + t;
      int row = c >> 3, ch = c & 7;
      int sch = ch ^ (row & 7);
      gload_lds16(fc + (size_t)(m0+row)*65536 + kk + sch*8, &Al[c*8]);
    }
    #pragma unroll
    for (int i = 0; i < 4; ++i){
      int c = i*256 + t;
      int row = c >> 3, ch = c & 7;
      int sch = ch ^ (row & 7);
      gload_lds16(WT + (size_t)(n0+row)*65536 + kk + sch*8, &Bl[c*8]);
    }
    __syncthreads();
    #pragma unroll
    for (int ks = 0; ks < 2; ++ks){
      short8 af[2], bf[4];
      #pragma unroll
      for (int rt = 0; rt < 2; ++rt){
        int row = wr + rt*16 + l15;
        int pch = (ks*4 + lg) ^ (row & 7);
        af[rt] = *(const short8*)&Al[row*64 + pch*8];
      }
      #pragma unroll
      for (int ct = 0; ct < 4; ++ct){
        int row = wc + ct*16 + l15;
        int pch = (ks*4 + lg) ^ (row & 7);
        bf[ct] = *(const short8*)&Bl[row*64 + pch*8];
      }
      #pragma unroll
      for (int rt = 0; rt < 2; ++rt)
        #pragma unroll
        for (int ct = 0; ct < 4; ++ct)
          acc[rt][ct] = __builtin_amdgcn_mfma_f32_16x16x32_bf16(
              af[rt], bf[ct], acc[rt][ct], 0, 0, 0);
    }
    __syncthreads();
  }

  float* Pb = P + (size_t)ksb * 131072;
  #pragma unroll
  for (int rt = 0; rt < 2; ++rt)
    #pragma unroll
    for (int ct = 0; ct < 4; ++ct)
      #pragma unroll
      for (int r = 0; r < 4; ++r){
        int row = m0 + wr + rt*16 + lg*4 + r;
        int col = n0 + wc + ct*16 + l15;
        Pb[(size_t)row*256 + col] = acc[rt][ct][r];
      }
}

// ---------------------------------------------------------------------------
// k_reduce: z1[row][j] = sum_ks P[ks][row][j]; fused BN1 stats partials ->
// atomicAdd into SQ1. 256 blocks x 2 rows, float2 per thread.
// ---------------------------------------------------------------------------
__global__ __launch_bounds__(256) void k_reduce(const float* __restrict__ P,
                                                float* __restrict__ z,
                                                float2* __restrict__ SQ1){
  __shared__ float4 ex[128];
  const int t = threadIdx.x;
  const int row = blockIdx.x*2 + (t >> 7);
  const int c2  = (t & 127) * 2;
  float sx = 0.f, sy = 0.f;
  #pragma unroll 8
  for (int ks = 0; ks < 64; ++ks){
    const float* p = &P[(size_t)ks*131072 + row*256 + c2];
    sx += p[0]; sy += p[1];
  }
  z[row*256 + c2]     = sx;
  z[row*256 + c2 + 1] = sy;
  if (t >= 128) ex[t & 127] = make_float4(sx, sx*sx, sy, sy*sy);
  __syncthreads();
  if (t < 128){
    float4 o = ex[t];
    atomicAdd(&SQ1[c2].x,     sx + o.x);
    atomicAdd(&SQ1[c2].y,     sx*sx + o.y);
    atomicAdd(&SQ1[c2 + 1].x, sy + o.z);
    atomicAdd(&SQ1[c2 + 1].y, sy*sy + o.w);
  }
}

// ---------------------------------------------------------------------------
// k_sgm: weight-stationary MFMA layer. 16 rows/block, NCOLS cols/block.
// zout = [relu(bn(zin)) | es?] @ W; BN stats of zout -> atomicAdd SQout.
// B = WTl_g (bf16 [256col][KK]) staged in LDS (k_gemm swizzle); A in regs.
// ---------------------------------------------------------------------------
template<int KK, int NC64, bool CAT>
__global__ __launch_bounds__(256) void k_sgm(const float* __restrict__ zin,
                                             const float* __restrict__ es,
                                             const unsigned short* __restrict__ WTl_g,
                                             const float2* __restrict__ SQin,
                                             const float* __restrict__ g,
                                             const float* __restrict__ be,
                                             float2* __restrict__ SQout,
                                             float* __restrict__ zout){
  constexpr int NCOLS = NC64 * 64;
  constexpr int NP = KK / 64;
  __shared__ unsigned short Bl[NP][NCOLS*64];
  __shared__ float2 ssl[256];
  const int r0 = blockIdx.x * 16;
  const int n0 = blockIdx.y * NCOLS;
  const int b  = r0 >> 6;
  const int t = threadIdx.x;
  const int l = t & 63, l15 = l & 15, lg = (l >> 4) & 3;
  const int w = t >> 6;
  const int wc = w * (NCOLS/4);

  // stage B panels (issue first; barrier below drains)
  #pragma unroll
  for (int p = 0; p < NP; ++p){
    #pragma unroll
    for (int i = 0; i < NCOLS*8/256; ++i){
      int c = i*256 + t;
      int row = c >> 3, ch = c & 7;
      int sch = ch ^ (row & 7);
      gload_lds16(WTl_g + (size_t)(n0+row)*KK + p*64 + sch*8, &Bl[p][c*8]);
    }
  }
  // input-layer BN coefficients
  {
    float2 sq = SQin[t];
    float mu  = sq.x * (1.f/512.f);
    float var = sq.y * (1.f/512.f) - mu*mu;
    float sc  = g[t] * rsqrtf(var + 1e-5f);
    ssl[t] = make_float2(sc, be[t] - mu*sc);
  }
  __syncthreads();

  // A fragments in registers: row = r0 + l15
  short8 a[KK/32];
  #pragma unroll
  for (int ks = 0; ks < KK/32; ++ks){
    int k = ks*32 + lg*8;
    short8 v;
    if (!CAT || k < 256){
      f32x4 lo = *(const f32x4*)&zin[(size_t)(r0+l15)*256 + k];
      f32x4 hi = *(const f32x4*)&zin[(size_t)(r0+l15)*256 + k + 4];
      #pragma unroll
      for (int j = 0; j < 4; ++j){
        float2 sv0 = ssl[k+j];
        float2 sv1 = ssl[k+4+j];
        v[j]   = (short)f2bf(fmaxf(lo[j]*sv0.x + sv0.y, 0.f));
        v[4+j] = (short)f2bf(fmaxf(hi[j]*sv1.x + sv1.y, 0.f));
      }
    } else {
      f32x4 lo = *(const f32x4*)&es[b*256 + (k-256)];
      f32x4 hi = *(const f32x4*)&es[b*256 + (k-256) + 4];
      #pragma unroll
      for (int j = 0; j < 4; ++j){
        v[j]   = (short)f2bf(lo[j]);
        v[4+j] = (short)f2bf(hi[j]);
      }
    }
    a[ks] = v;
  }

  f32x4 acc[NC64];
  #pragma unroll
  for (int ct = 0; ct < NC64; ++ct) acc[ct] = (f32x4){0.f,0.f,0.f,0.f};
  #pragma unroll
  for (int ks = 0; ks < KK/32; ++ks){
    int p = ks >> 1;
    int kin = (ks & 1) * 4;
    #pragma unroll
    for (int ct = 0; ct < NC64; ++ct){
      int row = wc + ct*16 + l15;
      int pch = (kin + lg) ^ (row & 7);
      short8 bfr = *(const short8*)&Bl[p][row*64 + pch*8];
      acc[ct] = __builtin_amdgcn_mfma_f32_16x16x32_bf16(a[ks], bfr, acc[ct], 0, 0, 0);
    }
  }

  #pragma unroll
  for (int ct = 0; ct < NC64; ++ct){
    int col = n0 + wc + ct*16 + l15;
    #pragma unroll
    for (int r = 0; r < 4; ++r)
      zout[(size_t)(r0 + lg*4 + r)*256 + col] = acc[ct][r];
    float S = acc[ct][0] + acc[ct][1] + acc[ct][2] + acc[ct][3];
    float Q = acc[ct][0]*acc[ct][0] + acc[ct][1]*acc[ct][1]
            + acc[ct][2]*acc[ct][2] + acc[ct][3]*acc[ct][3];
    S += __shfl_xor(S, 16); S += __shfl_xor(S, 32);
    Q += __shfl_xor(Q, 16); Q += __shfl_xor(Q, 32);
    if ((l >> 4) == 0){
      atomicAdd(&SQout[col].x, S);
      atomicAdd(&SQout[col].y, Q);
    }
  }
}

// ---------------------------------------------------------------------------
// k_qmean: per b: hm = mean_t relu(bn4(z4)); q = hm @ qW + qb. (bn from SQ4)
// ---------------------------------------------------------------------------
__global__ __launch_bounds__(256) void k_qmean(const float* __restrict__ z4,
                                               const float2* __restrict__ SQ4,
                                               const float* __restrict__ g,
                                               const float* __restrict__ be,
                                               const float* __restrict__ qW,
                                               const float* __restrict__ qb,
                                               float* __restrict__ q){
  __shared__ float Wl[2][64*256];
  __shared__ float hm[256];
  const int b = blockIdx.x, t = threadIdx.x;
  float2 sq = SQ4[t];
  float mu  = sq.x * (1.f/512.f);
  float var = sq.y * (1.f/512.f) - mu*mu;
  float sc  = g[t] * rsqrtf(var + 1e-5f);
  float sh  = be[t] - mu*sc;
  float s = 0.f;
  #pragma unroll 8
  for (int tt = 0; tt < 64; ++tt)
    s += fmaxf(z4[((b<<6)+tt)*256 + t]*sc + sh, 0.f);
  hm[t] = s * (1.f/64.f);
  auto stage = [&](int bb, int c0){
    const float* Wg = qW + (size_t)c0 * 64 * 256;
    #pragma unroll
    for (int i = 0; i < 16; ++i){
      int c = i*256 + t;
      gload_lds16(Wg + c*4, &Wl[bb][c*4]);
    }
  };
  stage(0, 0);
  float a = 0.f;
  int cur = 0;
  for (int c = 0; c < 4; ++c){
    __syncthreads();
    if (c < 3) stage(cur ^ 1, c + 1);
    #pragma unroll 16
    for (int k = 0; k < 64; ++k)
      a += hm[c*64 + k] * Wl[cur][k*256 + t];
    cur ^= 1;
  }
  q[b*256 + t] = a + qb[t];
}

// ---------------------------------------------------------------------------
// k_att2: 16 rows/block. Hh = relu(bn4(z4)); kvec = Hh@kW + kb;
// s = dot(q_b, kvec)/16; out = Hh * sigmoid(s). MFMA weight-stationary.
// ---------------------------------------------------------------------------
__global__ __launch_bounds__(256) void k_att2(const float* __restrict__ z4,
                                              const float2* __restrict__ SQ4,
                                              const float* __restrict__ g,
                                              const float* __restrict__ be,
                                              const unsigned short* __restrict__ kWT,
                                              const float* __restrict__ kb,
                                              const float* __restrict__ qv,
                                              float* __restrict__ out){
  __shared__ unsigned short Bl[4][256*64];
  __shared__ float2 ssl[256];
  __shared__ float Hh[16][260];
  __shared__ float pr[4][16];
  __shared__ float sig[16];
  const int r0 = blockIdx.x * 16;
  const int b  = r0 >> 6;
  const int t = threadIdx.x;
  const int l = t & 63, l15 = l & 15, lg = (l >> 4) & 3;
  const int w = t >> 6;
  const int wc = w * 64;

  #pragma unroll
  for (int p = 0; p < 4; ++p){
    #pragma unroll
    for (int i = 0; i < 8; ++i){
      int c = i*256 + t;
      int row = c >> 3, ch = c & 7;
      int sch = ch ^ (row & 7);
      gload_lds16(kWT + (size_t)row*256 + p*64 + sch*8, &Bl[p][c*8]);
    }
  }
  {
    float2 sq = SQ4[t];
    float mu  = sq.x * (1.f/512.f);
    float var = sq.y * (1.f/512.f) - mu*mu;
    float sc  = g[t] * rsqrtf(var + 1e-5f);
    ssl[t] = make_float2(sc, be[t] - mu*sc);
  }
  __syncthreads();

  short8 a[8];
  #pragma unroll
  for (int ks = 0; ks < 8; ++ks){
    int k = ks*32 + lg*8;
    f32x4 lo = *(const f32x4*)&z4[(size_t)(r0+l15)*256 + k];
    f32x4 hi = *(const f32x4*)&z4[(size_t)(r0+l15)*256 + k + 4];
    short8 v;
    f32x4 h0, h1;
    #pragma unroll
    for (int j = 0; j < 4; ++j){
      float2 sv0 = ssl[k+j];
      float2 sv1 = ssl[k+4+j];
      float x0 = fmaxf(lo[j]*sv0.x + sv0.y, 0.f);
      float x1 = fmaxf(hi[j]*sv1.x + sv1.y, 0.f);
      h0[j] = x0; h1[j] = x1;
      v[j]   = (short)f2bf(x0);
      v[4+j] = (short)f2bf(x1);
    }
    a[ks] = v;
    *(f32x4*)&Hh[l15][k]     = h0;
    *(f32x4*)&Hh[l15][k + 4] = h1;
  }

  f32x4 acc[4];
  #pragma unroll
  for (int ct = 0; ct < 4; ++ct) acc[ct] = (f32x4){0.f,0.f,0.f,0.f};
  #pragma unroll
  for (int ks = 0; ks < 8; ++ks){
    int p = ks >> 1;
    int kin = (ks & 1) * 4;
    #pragma unroll
    for (int ct = 0; ct < 4; ++ct){
      int row = wc + ct*16 + l15;
      int pch = (kin + lg) ^ (row & 7);
      short8 bfr = *(const short8*)&Bl[p][row*64 + pch*8];
      acc[ct] = __builtin_amdgcn_mfma_f32_16x16x32_bf16(a[ks], bfr, acc[ct], 0, 0, 0);
    }
  }

  float p4[4] = {0.f, 0.f, 0.f, 0.f};
  #pragma unroll
  for (int ct = 0; ct < 4; ++ct){
    int col = wc + ct*16 + l15;
    float qc  = qv[b*256 + col];
    float kbc = kb[col];
    #pragma unroll
    for (int r = 0; r < 4; ++r) p4[r] += (acc[ct][r] + kbc) * qc;
  }
  #pragma unroll
  for (int r = 0; r < 4; ++r){
    p4[r] += __shfl_xor(p4[r], 1);
    p4[r] += __shfl_xor(p4[r], 2);
    p4[r] += __shfl_xor(p4[r], 4);
    p4[r] += __shfl_xor(p4[r], 8);
  }
  if (l15 == 0){
    #pragma unroll
    for (int r = 0; r < 4; ++r) pr[w][lg*4 + r] = p4[r];
  }
  __syncthreads();
  if (t < 16){
    float s = pr[0][t] + pr[1][t] + pr[2][t] + pr[3][t];
    sig[t] = 1.f / (1.f + __expf(-s * (1.f/16.f)));
  }
  __syncthreads();
  #pragma unroll
  for (int r = 0; r < 16; ++r)
    out[(size_t)(r0+r)*256 + t] = Hh[r][t] * sig[r];
}

// ---------------------------------------------------------------------------
extern "C" void kernel_launch(void* const* d_in, const int* in_sizes, int n_in,
                              void* d_out, int out_size, void* d_ws, size_t ws_size,
                              hipStream_t stream){
  (void)in_sizes; (void)n_in; (void)out_size; (void)ws_size;
  const float* x    = (const float*)d_in[0];
  const float* e_s  = (const float*)d_in[1];
  const float* qW   = (const float*)d_in[2];
  const float* qb   = (const float*)d_in[3];
  const float* kW   = (const float*)d_in[4];
  const float* kb   = (const float*)d_in[5];
  const float* m1W  = (const float*)d_in[6];
  const float* m1g  = (const float*)d_in[8];
  const float* m1be = (const float*)d_in[9];
  const float* m2W  = (const float*)d_in[10];
  const float* m2g  = (const float*)d_in[12];
  const float* m2be = (const float*)d_in[13];
  const float* p1W  = (const float*)d_in[14];
  const float* p1g  = (const float*)d_in[16];
  const float* p1be = (const float*)d_in[17];
  const float* p2W  = (const float*)d_in[18];
  const float* p2g  = (const float*)d_in[20];
  const float* p2be = (const float*)d_in[21];
  // biases m1b,m2b,p1b,p2b cancel in BN — unused.

  char* ws = (char*)d_ws;
  unsigned short* WT  = (unsigned short*)ws; ws += 33554432;
  unsigned short* fc  = (unsigned short*)ws; ws += 67108864;
  float* P            = (float*)ws;  ws += 33554432;
  float* z1           = (float*)ws;  ws += 524288;
  float* z2           = (float*)ws;  ws += 524288;
  float* z3           = (float*)ws;  ws += 524288;
  float* z4           = (float*)ws;  ws += 524288;
  unsigned short* WTs = (unsigned short*)ws; ws += 655360;
  float2* SQ          = (float2*)ws; ws += 8192;   // SQ1..SQ4, 256 each
  float* qvv          = (float*)ws;  ws += 8192;
  float* out = (float*)d_out;

  const unsigned short* m2WT = WTs;
  const unsigned short* p1WT = WTs + 65536;
  const unsigned short* p2WT = WTs + 196608;
  const unsigned short* kWT  = WTs + 262144;
  float2* SQ1 = SQ, *SQ2 = SQ + 256, *SQ3 = SQ + 512, *SQ4 = SQ + 768;

  k_wt    <<<dim3(1024, 4), 256, 0, stream>>>(m1W, WT);
  k_wts   <<<dim3(20, 4), 256, 0, stream>>>(m2W, p1W, p2W, kW, WTs, SQ);
  k_corr  <<<512, 256, 0, stream>>>(x, fc);
  k_gemm  <<<1024, 256, 0, stream>>>(fc, WT, P);
  k_reduce<<<256, 256, 0, stream>>>(P, z1, SQ1);
  k_sgm<256,4,false><<<32, 256, 0, stream>>>(z1, nullptr, m2WT, SQ1, m1g, m1be, SQ2, z2);
  k_sgm<512,2,true> <<<dim3(32,2), 256, 0, stream>>>(z2, e_s, p1WT, SQ2, m2g, m2be, SQ3, z3);
  k_sgm<256,4,false><<<32, 256, 0, stream>>>(z3, nullptr, p2WT, SQ3, p1g, p1be, SQ4, z4);
  k_qmean <<<8, 256, 0, stream>>>(z4, SQ4, p2g, p2be, qW, qb, qvv);
  k_att2  <<<32, 256, 0, stream>>>(z4, SQ4, p2g, p2be, kWT, kb, qvv, out);
}

// Round 8
// 140.674 us; speedup vs baseline: 1.4315x; 1.0159x over previous
//
#include <hip/hip_runtime.h>
#include <stdint.h>
#include <stddef.h>

// ---------------------------------------------------------------------------
// ModuleGARO: corr(256x256 per bt, 512 bt) -> [512,65536]@[65536,256] GEMM ->
// BN/ReLU chain -> sigmoid QK attention scale.
// Linear biases before BN cancel exactly (x - mu) -> m1b/m2b/p1b/p2b dropped.
// R8: ksplit 64->32 (P round-trip 67->33.5MB), k_wts merged into k_wt
// (same 16.6KB LDS arena -> no occupancy hit, one less launch).
// Tail = R7's MFMA weight-stationary kernels (verified).
// ws: WT 33.5MB | fc 67MB | P 16.8MB | z1..z4 | WTs 640KB | SQ | qv
// ---------------------------------------------------------------------------

typedef short short8 __attribute__((ext_vector_type(8)));
typedef float f32x4 __attribute__((ext_vector_type(4)));

#define DEV __device__ __forceinline__

DEV unsigned short f2bf(float f){
  union { float f; unsigned u; } v; v.f = f;
  unsigned r = v.u + 0x7FFFu + ((v.u >> 16) & 1u);   // RNE
  return (unsigned short)(r >> 16);
}
DEV float bf2f(unsigned short b){
  union { unsigned u; float f; } v; v.u = ((unsigned)b) << 16;
  return v.f;
}
DEV void gload_lds16(const void* g, void* l){
  __builtin_amdgcn_global_load_lds(
      (const __attribute__((address_space(1))) unsigned int*)g,
      (__attribute__((address_space(3))) unsigned int*)l, 16, 0, 0);
}

// ---------------------------------------------------------------------------
// k_wtall: blocks [0,1024)x4 = m1W transpose (WT); blocks [1024,1044)x4 =
// tail-weight transposes (WTs, R5-verified geometry) + SQ zeroing.
// Both paths use the same tile[64][65] arena (16.6KB) -> full occupancy.
// ---------------------------------------------------------------------------
__global__ __launch_bounds__(256) void k_wtall(const float* __restrict__ W,
                                               unsigned short* __restrict__ WT,
                                               const float* __restrict__ m2W,
                                               const float* __restrict__ p1W,
                                               const float* __restrict__ p2W,
                                               const float* __restrict__ kW,
                                               unsigned short* __restrict__ WTs,
                                               float2* __restrict__ SQ){
  __shared__ float tile[64][65];
  const int tr = threadIdx.x >> 6;   // 0..3
  const int tc = threadIdx.x & 63;

  if (blockIdx.x >= 1024){
    const int bx = blockIdx.x - 1024;          // 0..19
    if (bx == 0 && blockIdx.y == 0){
      for (int i = threadIdx.x; i < 1024; i += 256) SQ[i] = make_float2(0.f, 0.f);
    }
    const float* Ws; int K; size_t dst; int kt;
    if (bx < 4)       { Ws = m2W; K = 256; dst = 0;      kt = bx; }
    else if (bx < 12) { Ws = p1W; K = 512; dst = 65536;  kt = bx - 4; }
    else if (bx < 16) { Ws = p2W; K = 256; dst = 196608; kt = bx - 12; }
    else              { Ws = kW;  K = 256; dst = 262144; kt = bx - 16; }
    const int k0 = kt*64, o0 = blockIdx.y*64;
    #pragma unroll
    for (int i = 0; i < 16; ++i){
      int kr = i*4 + tr;
      tile[kr][tc] = Ws[(size_t)(k0+kr)*256 + o0 + tc];
    }
    __syncthreads();
    #pragma unroll
    for (int i = 0; i < 16; ++i){
      int orow = i*4 + tr;
      WTs[dst + (size_t)(o0+orow)*K + k0 + tc] = f2bf(tile[tc][orow]);
    }
    return;
  }

  const int k0 = blockIdx.x * 64;
  const int o0 = blockIdx.y * 64;
  #pragma unroll
  for (int i = 0; i < 16; ++i){
    int kr = i*4 + tr;
    tile[kr][tc] = W[(size_t)(k0+kr)*256 + o0 + tc];
  }
  __syncthreads();
  #pragma unroll
  for (int i = 0; i < 16; ++i){
    int orow = i*4 + tr;
    WT[(size_t)(o0+orow)*65536 + k0 + tc] = f2bf(tile[tc][orow]);
  }
}

// ---------------------------------------------------------------------------
// k_corr: one block per bt. corr = (y^T y) * rs_i * rs_j, clip, bf16. (R4)
// ---------------------------------------------------------------------------
__global__ __launch_bounds__(256) void k_corr(const float* __restrict__ x,
                                              unsigned short* __restrict__ fc){
  __shared__ unsigned short yT[256*72];
  __shared__ float rs[256];
  __shared__ unsigned short stg[4][64*40];
  const int bt = blockIdx.x;
  const float* xb = x + (size_t)bt * 16384;   // 64 samples x 256 vars
  const int i = threadIdx.x;

  float sum = 0.f;
  #pragma unroll 8
  for (int s = 0; s < 64; ++s) sum += xb[s*256 + i];
  const float mean = sum * (1.f/64.f);

  float ss = 0.f;
  unsigned int* yT32 = (unsigned int*)yT;
  #pragma unroll 4
  for (int s = 0; s < 64; s += 2){
    float v0 = xb[s*256 + i] - mean;
    float v1 = xb[(s+1)*256 + i] - mean;
    unsigned short b0 = f2bf(v0), b1 = f2bf(v1);
    float r0 = bf2f(b0), r1 = bf2f(b1);
    ss += r0*r0 + r1*r1;
    yT32[(i*72 + s) >> 1] = (unsigned)b0 | ((unsigned)b1 << 16);
  }
  rs[i] = rsqrtf(ss);
  __syncthreads();

  const int w   = threadIdx.x >> 6;
  const int l   = threadIdx.x & 63;
  const int l15 = l & 15, lg = l >> 4;

  short8 RF[4][2];
  #pragma unroll
  for (int rt = 0; rt < 4; ++rt){
    int row = w*64 + rt*16 + l15;
    #pragma unroll
    for (int ks = 0; ks < 2; ++ks)
      RF[rt][ks] = *(const short8*)&yT[row*72 + ks*32 + lg*8];
  }
  float rrow[4][4];
  #pragma unroll
  for (int rt = 0; rt < 4; ++rt)
    #pragma unroll
    for (int r = 0; r < 4; ++r)
      rrow[rt][r] = rs[w*64 + rt*16 + lg*4 + r];

  unsigned short* sg = stg[w];
  for (int cc = 0; cc < 8; ++cc){
    short8 CF[2][2];
    #pragma unroll
    for (int ct = 0; ct < 2; ++ct){
      int col = cc*32 + ct*16 + l15;
      #pragma unroll
      for (int ks = 0; ks < 2; ++ks)
        CF[ct][ks] = *(const short8*)&yT[col*72 + ks*32 + lg*8];
    }
    f32x4 acc[4][2];
    #pragma unroll
    for (int rt = 0; rt < 4; ++rt)
      #pragma unroll
      for (int ct = 0; ct < 2; ++ct)
        acc[rt][ct] = (f32x4){0.f,0.f,0.f,0.f};
    #pragma unroll
    for (int ks = 0; ks < 2; ++ks)
      #pragma unroll
      for (int rt = 0; rt < 4; ++rt)
        #pragma unroll
        for (int ct = 0; ct < 2; ++ct)
          acc[rt][ct] = __builtin_amdgcn_mfma_f32_16x16x32_bf16(
              RF[rt][ks], CF[ct][ks], acc[rt][ct], 0, 0, 0);

    float rc[2] = { rs[cc*32 + l15], rs[cc*32 + 16 + l15] };
    #pragma unroll
    for (int rt = 0; rt < 4; ++rt)
      #pragma unroll
      for (int ct = 0; ct < 2; ++ct)
        #pragma unroll
        for (int r = 0; r < 4; ++r){
          float v = acc[rt][ct][r] * rrow[rt][r] * rc[ct];
          v = fminf(fmaxf(v, -1.f), 1.f);
          sg[(rt*16 + lg*4 + r)*40 + ct*16 + l15] = f2bf(v);
        }
    #pragma unroll
    for (int idx = 0; idx < 4; ++idx){
      int c = idx*64 + l;
      int rowL = c >> 2, ch = c & 3;
      short8 v = *(const short8*)&sg[rowL*40 + ch*8];
      *(short8*)&fc[(size_t)bt*65536 + (size_t)(w*64 + rowL)*256 + cc*32 + ch*8] = v;
    }
  }
}

// ---------------------------------------------------------------------------
// k_gemm: [512,65536]bf16 @ WT^T -> split-K fp32 partials. R8: ksplit=32,
// K=2048/block (32 iters), grid 512 = 2 blocks/CU. BM=64, BN=128, BK=64.
// XCD swizzle: chunk/XCD = 4 ksb x 16 (m,n) -> 4MB B-slice L2-resident.
// ---------------------------------------------------------------------------
__global__ __launch_bounds__(256) void k_gemm(const unsigned short* __restrict__ fc,
                                              const unsigned short* __restrict__ WT,
                                              float* __restrict__ P){
  __shared__ unsigned short Al[64*64];
  __shared__ unsigned short Bl[128*64];
  const int bid  = blockIdx.x;
  const int wgid = (bid & 7)*64 + (bid >> 3);   // bijective (512 % 8 == 0)
  const int ksb  = wgid >> 4;                   // 0..31
  const int rem  = wgid & 15;
  const int n0   = (rem >> 3) * 128;
  const int m0   = (rem & 7) * 64;
  const int k0   = ksb * 2048;
  const int t    = threadIdx.x;
  const int w = t >> 6, l = t & 63, l15 = l & 15, lg = l >> 4;
  const int wr = (w >> 1) * 32;
  const int wc = (w & 1) * 64;

  f32x4 acc[2][4];
  #pragma unroll
  for (int a = 0; a < 2; ++a)
    #pragma unroll
    for (int b = 0; b < 4; ++b) acc[a][b] = (f32x4){0.f,0.f,0.f,0.f};

  for (int kt = 0; kt < 32; ++kt){
    const int kk = k0 + kt*64;
    #pragma unroll
    for (int i = 0; i < 2; ++i){
      int c = i*256 + t;
      int row = c >> 3, ch = c & 7;
      int sch = ch ^ (row & 7);
      gload_lds16(fc + (size_t)(m0+row)*65536 + kk + sch*8, &Al[c*8]);
    }
    #pragma unroll
    for (int i = 0; i < 4; ++i){
      int c = i*256 + t;
      int row = c >> 3, ch = c & 7;
      int sch = ch ^ (row & 7);
      gload_lds16(WT + (size_t)(n0+row)*65536 + kk + sch*8, &Bl[c*8]);
    }
    __syncthreads();
    #pragma unroll
    for (int ks = 0; ks < 2; ++ks){
      short8 af[2], bf[4];
      #pragma unroll
      for (int rt = 0; rt < 2; ++rt){
        int row = wr + rt*16 + l15;
        int pch = (ks*4 + lg) ^ (row & 7);
        af[rt] = *(const short8*)&Al[row*64 + pch*8];
      }
      #pragma unroll
      for (int ct = 0; ct < 4; ++ct){
        int row = wc + ct*16 + l15;
        int pch = (ks*4 + lg) ^ (row & 7);
        bf[ct] = *(const short8*)&Bl[row*64 + pch*8];
      }
      #pragma unroll
      for (int rt = 0; rt < 2; ++rt)
        #pragma unroll
        for (int ct = 0; ct < 4; ++ct)
          acc[rt][ct] = __builtin_amdgcn_mfma_f32_16x16x32_bf16(
              af[rt], bf[ct], acc[rt][ct], 0, 0, 0);
    }
    __syncthreads();
  }

  float* Pb = P + (size_t)ksb * 131072;
  #pragma unroll
  for (int rt = 0; rt < 2; ++rt)
    #pragma unroll
    for (int ct = 0; ct < 4; ++ct)
      #pragma unroll
      for (int r = 0; r < 4; ++r){
        int row = m0 + wr + rt*16 + lg*4 + r;
        int col = n0 + wc + ct*16 + l15;
        Pb[(size_t)row*256 + col] = acc[rt][ct][r];
      }
}

// ---------------------------------------------------------------------------
// k_reduce: z1[row][j] = sum_{ks<32} P[ks][row][j]; fused BN1 stats ->
// atomicAdd into SQ1. 256 blocks x 2 rows, float2 per thread.
// ---------------------------------------------------------------------------
__global__ __launch_bounds__(256) void k_reduce(const float* __restrict__ P,
                                                float* __restrict__ z,
                                                float2* __restrict__ SQ1){
  __shared__ float4 ex[128];
  const int t = threadIdx.x;
  const int row = blockIdx.x*2 + (t >> 7);
  const int c2  = (t & 127) * 2;
  float sx = 0.f, sy = 0.f;
  #pragma unroll 8
  for (int ks = 0; ks < 32; ++ks){
    const float* p = &P[(size_t)ks*131072 + row*256 + c2];
    sx += p[0]; sy += p[1];
  }
  z[row*256 + c2]     = sx;
  z[row*256 + c2 + 1] = sy;
  if (t >= 128) ex[t & 127] = make_float4(sx, sx*sx, sy, sy*sy);
  __syncthreads();
  if (t < 128){
    float4 o = ex[t];
    atomicAdd(&SQ1[c2].x,     sx + o.x);
    atomicAdd(&SQ1[c2].y,     sx*sx + o.y);
    atomicAdd(&SQ1[c2 + 1].x, sy + o.z);
    atomicAdd(&SQ1[c2 + 1].y, sy*sy + o.w);
  }
}

// ---------------------------------------------------------------------------
// k_sgm: weight-stationary MFMA layer. 16 rows/block, NCOLS cols/block.
// zout = [relu(bn(zin)) | es?] @ W; BN stats of zout -> atomicAdd SQout.
// ---------------------------------------------------------------------------
template<int KK, int NC64, bool CAT>
__global__ __launch_bounds__(256) void k_sgm(const float* __restrict__ zin,
                                             const float* __restrict__ es,
                                             const unsigned short* __restrict__ WTl_g,
                                             const float2* __restrict__ SQin,
                                             const float* __restrict__ g,
                                             const float* __restrict__ be,
                                             float2* __restrict__ SQout,
                                             float* __restrict__ zout){
  constexpr int NCOLS = NC64 * 64;
  constexpr int NP = KK / 64;
  __shared__ unsigned short Bl[NP][NCOLS*64];
  __shared__ float2 ssl[256];
  const int r0 = blockIdx.x * 16;
  const int n0 = blockIdx.y * NCOLS;
  const int b  = r0 >> 6;
  const int t = threadIdx.x;
  const int l = t & 63, l15 = l & 15, lg = (l >> 4) & 3;
  const int w = t >> 6;
  const int wc = w * (NCOLS/4);

  #pragma unroll
  for (int p = 0; p < NP; ++p){
    #pragma unroll
    for (int i = 0; i < NCOLS*8/256; ++i){
      int c = i*256 + t;
      int row = c >> 3, ch = c & 7;
      int sch = ch ^ (row & 7);
      gload_lds16(WTl_g + (size_t)(n0+row)*KK + p*64 + sch*8, &Bl[p][c*8]);
    }
  }
  {
    float2 sq = SQin[t];
    float mu  = sq.x * (1.f/512.f);
    float var = sq.y * (1.f/512.f) - mu*mu;
    float sc  = g[t] * rsqrtf(var + 1e-5f);
    ssl[t] = make_float2(sc, be[t] - mu*sc);
  }
  __syncthreads();

  short8 a[KK/32];
  #pragma unroll
  for (int ks = 0; ks < KK/32; ++ks){
    int k = ks*32 + lg*8;
    short8 v;
    if (!CAT || k < 256){
      f32x4 lo = *(const f32x4*)&zin[(size_t)(r0+l15)*256 + k];
      f32x4 hi = *(const f32x4*)&zin[(size_t)(r0+l15)*256 + k + 4];
      #pragma unroll
      for (int j = 0; j < 4; ++j){
        float2 sv0 = ssl[k+j];
        float2 sv1 = ssl[k+4+j];
        v[j]   = (short)f2bf(fmaxf(lo[j]*sv0.x + sv0.y, 0.f));
        v[4+j] = (short)f2bf(fmaxf(hi[j]*sv1.x + sv1.y, 0.f));
      }
    } else {
      f32x4 lo = *(const f32x4*)&es[b*256 + (k-256)];
      f32x4 hi = *(const f32x4*)&es[b*256 + (k-256) + 4];
      #pragma unroll
      for (int j = 0; j < 4; ++j){
        v[j]   = (short)f2bf(lo[j]);
        v[4+j] = (short)f2bf(hi[j]);
      }
    }
    a[ks] = v;
  }

  f32x4 acc[NC64];
  #pragma unroll
  for (int ct = 0; ct < NC64; ++ct) acc[ct] = (f32x4){0.f,0.f,0.f,0.f};
  #pragma unroll
  for (int ks = 0; ks < KK/32; ++ks){
    int p = ks >> 1;
    int kin = (ks & 1) * 4;
    #pragma unroll
    for (int ct = 0; ct < NC64; ++ct){
      int row = wc + ct*16 + l15;
      int pch = (kin + lg) ^ (row & 7);
      short8 bfr = *(const short8*)&Bl[p][row*64 + pch*8];
      acc[ct] = __builtin_amdgcn_mfma_f32_16x16x32_bf16(a[ks], bfr, acc[ct], 0, 0, 0);
    }
  }

  #pragma unroll
  for (int ct = 0; ct < NC64; ++ct){
    int col = n0 + wc + ct*16 + l15;
    #pragma unroll
    for (int r = 0; r < 4; ++r)
      zout[(size_t)(r0 + lg*4 + r)*256 + col] = acc[ct][r];
    float S = acc[ct][0] + acc[ct][1] + acc[ct][2] + acc[ct][3];
    float Q = acc[ct][0]*acc[ct][0] + acc[ct][1]*acc[ct][1]
            + acc[ct][2]*acc[ct][2] + acc[ct][3]*acc[ct][3];
    S += __shfl_xor(S, 16); S += __shfl_xor(S, 32);
    Q += __shfl_xor(Q, 16); Q += __shfl_xor(Q, 32);
    if ((l >> 4) == 0){
      atomicAdd(&SQout[col].x, S);
      atomicAdd(&SQout[col].y, Q);
    }
  }
}

// ---------------------------------------------------------------------------
// k_qmean: per b: hm = mean_t relu(bn4(z4)); q = hm @ qW + qb. (bn from SQ4)
// ---------------------------------------------------------------------------
__global__ __launch_bounds__(256) void k_qmean(const float* __restrict__ z4,
                                               const float2* __restrict__ SQ4,
                                               const float* __restrict__ g,
                                               const float* __restrict__ be,
                                               const float* __restrict__ qW,
                                               const float* __restrict__ qb,
                                               float* __restrict__ q){
  __shared__ float Wl[2][64*256];
  __shared__ float hm[256];
  const int b = blockIdx.x, t = threadIdx.x;
  float2 sq = SQ4[t];
  float mu  = sq.x * (1.f/512.f);
  float var = sq.y * (1.f/512.f) - mu*mu;
  float sc  = g[t] * rsqrtf(var + 1e-5f);
  float sh  = be[t] - mu*sc;
  float s = 0.f;
  #pragma unroll 8
  for (int tt = 0; tt < 64; ++tt)
    s += fmaxf(z4[((b<<6)+tt)*256 + t]*sc + sh, 0.f);
  hm[t] = s * (1.f/64.f);
  auto stage = [&](int bb, int c0){
    const float* Wg = qW + (size_t)c0 * 64 * 256;
    #pragma unroll
    for (int i = 0; i < 16; ++i){
      int c = i*256 + t;
      gload_lds16(Wg + c*4, &Wl[bb][c*4]);
    }
  };
  stage(0, 0);
  float a = 0.f;
  int cur = 0;
  for (int c = 0; c < 4; ++c){
    __syncthreads();
    if (c < 3) stage(cur ^ 1, c + 1);
    #pragma unroll 16
    for (int k = 0; k < 64; ++k)
      a += hm[c*64 + k] * Wl[cur][k*256 + t];
    cur ^= 1;
  }
  q[b*256 + t] = a + qb[t];
}

// ---------------------------------------------------------------------------
// k_att2: 16 rows/block. Hh = relu(bn4(z4)); kvec = Hh@kW + kb;
// s = dot(q_b, kvec)/16; out = Hh * sigmoid(s). MFMA weight-stationary.
// ---------------------------------------------------------------------------
__global__ __launch_bounds__(256) void k_att2(const float* __restrict__ z4,
                                              const float2* __restrict__ SQ4,
                                              const float* __restrict__ g,
                                              const float* __restrict__ be,
                                              const unsigned short* __restrict__ kWT,
                                              const float* __restrict__ kb,
                                              const float* __restrict__ qv,
                                              float* __restrict__ out){
  __shared__ unsigned short Bl[4][256*64];
  __shared__ float2 ssl[256];
  __shared__ float Hh[16][260];
  __shared__ float pr[4][16];
  __shared__ float sig[16];
  const int r0 = blockIdx.x * 16;
  const int b  = r0 >> 6;
  const int t = threadIdx.x;
  const int l = t & 63, l15 = l & 15, lg = (l >> 4) & 3;
  const int w = t >> 6;
  const int wc = w * 64;

  #pragma unroll
  for (int p = 0; p < 4; ++p){
    #pragma unroll
    for (int i = 0; i < 8; ++i){
      int c = i*256 + t;
      int row = c >> 3, ch = c & 7;
      int sch = ch ^ (row & 7);
      gload_lds16(kWT + (size_t)row*256 + p*64 + sch*8, &Bl[p][c*8]);
    }
  }
  {
    float2 sq = SQ4[t];
    float mu  = sq.x * (1.f/512.f);
    float var = sq.y * (1.f/512.f) - mu*mu;
    float sc  = g[t] * rsqrtf(var + 1e-5f);
    ssl[t] = make_float2(sc, be[t] - mu*sc);
  }
  __syncthreads();

  short8 a[8];
  #pragma unroll
  for (int ks = 0; ks < 8; ++ks){
    int k = ks*32 + lg*8;
    f32x4 lo = *(const f32x4*)&z4[(size_t)(r0+l15)*256 + k];
    f32x4 hi = *(const f32x4*)&z4[(size_t)(r0+l15)*256 + k + 4];
    short8 v;
    f32x4 h0, h1;
    #pragma unroll
    for (int j = 0; j < 4; ++j){
      float2 sv0 = ssl[k+j];
      float2 sv1 = ssl[k+4+j];
      float x0 = fmaxf(lo[j]*sv0.x + sv0.y, 0.f);
      float x1 = fmaxf(hi[j]*sv1.x + sv1.y, 0.f);
      h0[j] = x0; h1[j] = x1;
      v[j]   = (short)f2bf(x0);
      v[4+j] = (short)f2bf(x1);
    }
    a[ks] = v;
    *(f32x4*)&Hh[l15][k]     = h0;
    *(f32x4*)&Hh[l15][k + 4] = h1;
  }

  f32x4 acc[4];
  #pragma unroll
  for (int ct = 0; ct < 4; ++ct) acc[ct] = (f32x4){0.f,0.f,0.f,0.f};
  #pragma unroll
  for (int ks = 0; ks < 8; ++ks){
    int p = ks >> 1;
    int kin = (ks & 1) * 4;
    #pragma unroll
    for (int ct = 0; ct < 4; ++ct){
      int row = wc + ct*16 + l15;
      int pch = (kin + lg) ^ (row & 7);
      short8 bfr = *(const short8*)&Bl[p][row*64 + pch*8];
      acc[ct] = __builtin_amdgcn_mfma_f32_16x16x32_bf16(a[ks], bfr, acc[ct], 0, 0, 0);
    }
  }

  float p4[4] = {0.f, 0.f, 0.f, 0.f};
  #pragma unroll
  for (int ct = 0; ct < 4; ++ct){
    int col = wc + ct*16 + l15;
    float qc  = qv[b*256 + col];
    float kbc = kb[col];
    #pragma unroll
    for (int r = 0; r < 4; ++r) p4[r] += (acc[ct][r] + kbc) * qc;
  }
  #pragma unroll
  for (int r = 0; r < 4; ++r){
    p4[r] += __shfl_xor(p4[r], 1);
    p4[r] += __shfl_xor(p4[r], 2);
    p4[r] += __shfl_xor(p4[r], 4);
    p4[r] += __shfl_xor(p4[r], 8);
  }
  if (l15 == 0){
    #pragma unroll
    for (int r = 0; r < 4; ++r) pr[w][lg*4 + r] = p4[r];
  }
  __syncthreads();
  if (t < 16){
    float s = pr[0][t] + pr[1][t] + pr[2][t] + pr[3][t];
    sig[t] = 1.f / (1.f + __expf(-s * (1.f/16.f)));
  }
  __syncthreads();
  #pragma unroll
  for (int r = 0; r < 16; ++r)
    out[(size_t)(r0+r)*256 + t] = Hh[r][t] * sig[r];
}

// ---------------------------------------------------------------------------
extern "C" void kernel_launch(void* const* d_in, const int* in_sizes, int n_in,
                              void* d_out, int out_size, void* d_ws, size_t ws_size,
                              hipStream_t stream){
  (void)in_sizes; (void)n_in; (void)out_size; (void)ws_size;
  const float* x    = (const float*)d_in[0];
  const float* e_s  = (const float*)d_in[1];
  const float* qW   = (const float*)d_in[2];
  const float* qb   = (const float*)d_in[3];
  const float* kW   = (const float*)d_in[4];
  const float* kb   = (const float*)d_in[5];
  const float* m1W  = (const float*)d_in[6];
  const float* m1g  = (const float*)d_in[8];
  const float* m1be = (const float*)d_in[9];
  const float* m2W  = (const float*)d_in[10];
  const float* m2g  = (const float*)d_in[12];
  const float* m2be = (const float*)d_in[13];
  const float* p1W  = (const float*)d_in[14];
  const float* p1g  = (const float*)d_in[16];
  const float* p1be = (const float*)d_in[17];
  const float* p2W  = (const float*)d_in[18];
  const float* p2g  = (const float*)d_in[20];
  const float* p2be = (const float*)d_in[21];
  // biases m1b,m2b,p1b,p2b cancel in BN — unused.

  char* ws = (char*)d_ws;
  unsigned short* WT  = (unsigned short*)ws; ws += 33554432;
  unsigned short* fc  = (unsigned short*)ws; ws += 67108864;
  float* P            = (float*)ws;  ws += 33554432;   // 16.8MB used (ksplit=32)
  float* z1           = (float*)ws;  ws += 524288;
  float* z2           = (float*)ws;  ws += 524288;
  float* z3           = (float*)ws;  ws += 524288;
  float* z4           = (float*)ws;  ws += 524288;
  unsigned short* WTs = (unsigned short*)ws; ws += 655360;
  float2* SQ          = (float2*)ws; ws += 8192;   // SQ1..SQ4, 256 each
  float* qvv          = (float*)ws;  ws += 8192;
  float* out = (float*)d_out;

  const unsigned short* m2WT = WTs;
  const unsigned short* p1WT = WTs + 65536;
  const unsigned short* p2WT = WTs + 196608;
  const unsigned short* kWT  = WTs + 262144;
  float2* SQ1 = SQ, *SQ2 = SQ + 256, *SQ3 = SQ + 512, *SQ4 = SQ + 768;

  k_wtall <<<dim3(1044, 4), 256, 0, stream>>>(m1W, WT, m2W, p1W, p2W, kW, WTs, SQ);
  k_corr  <<<512, 256, 0, stream>>>(x, fc);
  k_gemm  <<<512, 256, 0, stream>>>(fc, WT, P);
  k_reduce<<<256, 256, 0, stream>>>(P, z1, SQ1);
  k_sgm<256,4,false><<<32, 256, 0, stream>>>(z1, nullptr, m2WT, SQ1, m1g, m1be, SQ2, z2);
  k_sgm<512,2,true> <<<dim3(32,2), 256, 0, stream>>>(z2, e_s, p1WT, SQ2, m2g, m2be, SQ3, z3);
  k_sgm<256,4,false><<<32, 256, 0, stream>>>(z3, nullptr, p2WT, SQ3, p1g, p1be, SQ4, z4);
  k_qmean <<<8, 256, 0, stream>>>(z4, SQ4, p2g, p2be, qW, qb, qvv);
  k_att2  <<<32, 256, 0, stream>>>(z4, SQ4, p2g, p2be, kWT, kb, qvv, out);
}

// Round 9
// 127.041 us; speedup vs baseline: 1.5851x; 1.1073x over previous
//
#include <hip/hip_runtime.h>
#include <stdint.h>
#include <stddef.h>

// ---------------------------------------------------------------------------
// ModuleGARO. R9: exploit corr symmetry. WTf[(i,j)] = W_ij+W_ji (j<i),
// W_ii (j==i), 0 (j>i); GEMM enumerates only k-tiles with jc <= i/64:
// 640 of 1024 tiles. corr computes/writes only needed lower-tri chunks,
// waves rebalanced {2w,2w+1,14-2w,15-2w} -> 20/32 chunks each.
// Tail = R7/R8 MFMA weight-stationary kernels (verified).
// ws: WTf 33.5MB | fc 67MB | P 21MB | z1..z4 | WTs 640KB | SQ | qv
// ---------------------------------------------------------------------------

typedef short short8 __attribute__((ext_vector_type(8)));
typedef float f32x4 __attribute__((ext_vector_type(4)));

#define DEV __device__ __forceinline__

DEV unsigned short f2bf(float f){
  union { float f; unsigned u; } v; v.f = f;
  unsigned r = v.u + 0x7FFFu + ((v.u >> 16) & 1u);   // RNE
  return (unsigned short)(r >> 16);
}
DEV float bf2f(unsigned short b){
  union { unsigned u; float f; } v; v.u = ((unsigned)b) << 16;
  return v.f;
}
DEV void gload_lds16(const void* g, void* l){
  __builtin_amdgcn_global_load_lds(
      (const __attribute__((address_space(1))) unsigned int*)g,
      (__attribute__((address_space(3))) unsigned int*)l, 16, 0, 0);
}

// decode triangle-tile index t (0..639) -> (i, jc):  bands a=0..3,
// i in [64a,64a+64), tiles per i = a+1, band prefix {0,64,192,384}.
DEV void tri_decode(int t, int& i, int& jc){
  int a, u;
  if (t < 64)       { a = 0; u = t; }
  else if (t < 192) { a = 1; u = t - 64; }
  else if (t < 384) { a = 2; u = t - 192; }
  else              { a = 3; u = t - 384; }
  int idx = (a == 0) ? u : (a == 1) ? (u >> 1) : (a == 2) ? (u / 3) : (u >> 2);
  jc = u - idx * (a + 1);
  i = 64*a + idx;
}

// ---------------------------------------------------------------------------
// k_wtf: blocks [0,2560) = folded transpose of m1W into WTf (tile t=bid>>2,
// o-tile = bid&3); blocks [2560,2640) = tail-weight transposes + SQ zero.
// ---------------------------------------------------------------------------
__global__ __launch_bounds__(256) void k_wtf(const float* __restrict__ W,
                                             unsigned short* __restrict__ WTf,
                                             const float* __restrict__ m2W,
                                             const float* __restrict__ p1W,
                                             const float* __restrict__ p2W,
                                             const float* __restrict__ kW,
                                             unsigned short* __restrict__ WTs,
                                             float2* __restrict__ SQ){
  __shared__ float tile [64][65];
  __shared__ float tile2[64][65];
  const int tr = threadIdx.x >> 6, tc = threadIdx.x & 63;
  const int bid = blockIdx.x;

  if (bid >= 2560){
    const int sub = bid - 2560;              // 0..79
    if (sub == 0){
      for (int i = threadIdx.x; i < 1024; i += 256) SQ[i] = make_float2(0.f, 0.f);
    }
    const int bx = sub >> 2, oy = sub & 3;
    const float* Ws; int K; size_t dst; int kt;
    if (bx < 4)       { Ws = m2W; K = 256; dst = 0;      kt = bx; }
    else if (bx < 12) { Ws = p1W; K = 512; dst = 65536;  kt = bx - 4; }
    else if (bx < 16) { Ws = p2W; K = 256; dst = 196608; kt = bx - 12; }
    else              { Ws = kW;  K = 256; dst = 262144; kt = bx - 16; }
    const int k0 = kt*64, o0 = oy*64;
    #pragma unroll
    for (int q = 0; q < 16; ++q){
      int kr = q*4 + tr;
      tile[kr][tc] = Ws[(size_t)(k0+kr)*256 + o0 + tc];
    }
    __syncthreads();
    #pragma unroll
    for (int q = 0; q < 16; ++q){
      int orow = q*4 + tr;
      WTs[dst + (size_t)(o0+orow)*K + k0 + tc] = f2bf(tile[tc][orow]);
    }
    return;
  }

  int i, jc;
  tri_decode(bid >> 2, i, jc);
  const int j0 = jc * 64;
  const int o0 = (bid & 3) * 64;
  #pragma unroll
  for (int q = 0; q < 16; ++q){
    int kr = q*4 + tr;
    tile [kr][tc] = W[(size_t)(i*256 + j0 + kr)*256 + o0 + tc];     // W[(i,j)][o]
    tile2[kr][tc] = W[(size_t)((j0 + kr)*256 + i)*256 + o0 + tc];   // W[(j,i)][o]
  }
  __syncthreads();
  #pragma unroll
  for (int q = 0; q < 16; ++q){
    int orow = q*4 + tr;
    int j = j0 + tc;
    float v = (j < i) ? (tile[tc][orow] + tile2[tc][orow])
            : (j == i) ? tile[tc][orow] : 0.f;
    WTf[(size_t)(o0+orow)*65536 + (size_t)i*256 + j0 + tc] = f2bf(v);
  }
}

// ---------------------------------------------------------------------------
// k_corr2: one block per bt; lower-triangle chunks only. Wave w owns rt-tiles
// {2w,2w+1,14-2w,15-2w} (16 rows each); chunk cc valid for tile iff
// cc <= 2*((rtile*16+15)>>6)+1. All waves: exactly 20 of 32 chunks.
// ---------------------------------------------------------------------------
__global__ __launch_bounds__(256) void k_corr2(const float* __restrict__ x,
                                               unsigned short* __restrict__ fc){
  __shared__ unsigned short yT[256*72];
  __shared__ float rs[256];
  __shared__ unsigned short stg[4][64*40];
  const int bt = blockIdx.x;
  const float* xb = x + (size_t)bt * 16384;
  const int i = threadIdx.x;

  float sum = 0.f;
  #pragma unroll 8
  for (int s = 0; s < 64; ++s) sum += xb[s*256 + i];
  const float mean = sum * (1.f/64.f);

  float ss = 0.f;
  unsigned int* yT32 = (unsigned int*)yT;
  #pragma unroll 4
  for (int s = 0; s < 64; s += 2){
    float v0 = xb[s*256 + i] - mean;
    float v1 = xb[(s+1)*256 + i] - mean;
    unsigned short b0 = f2bf(v0), b1 = f2bf(v1);
    float r0 = bf2f(b0), r1 = bf2f(b1);
    ss += r0*r0 + r1*r1;
    yT32[(i*72 + s) >> 1] = (unsigned)b0 | ((unsigned)b1 << 16);
  }
  rs[i] = rsqrtf(ss);
  __syncthreads();

  const int w   = threadIdx.x >> 6;
  const int l   = threadIdx.x & 63;
  const int l15 = l & 15, lg = l >> 4;

  const int rtiles[4] = {2*w, 2*w + 1, 14 - 2*w, 15 - 2*w};
  int ccmax[4];
  #pragma unroll
  for (int q = 0; q < 4; ++q)
    ccmax[q] = 2*((rtiles[q]*16 + 15) >> 6) + 1;

  short8 RF[4][2];
  float rrow[4][4];
  #pragma unroll
  for (int q = 0; q < 4; ++q){
    int row = rtiles[q]*16 + l15;
    #pragma unroll
    for (int ks = 0; ks < 2; ++ks)
      RF[q][ks] = *(const short8*)&yT[row*72 + ks*32 + lg*8];
    #pragma unroll
    for (int r = 0; r < 4; ++r)
      rrow[q][r] = rs[rtiles[q]*16 + lg*4 + r];
  }

  unsigned short* sg = stg[w];
  const int cclim = ccmax[3];                 // largest tile bounds the loop
  for (int cc = 0; cc <= cclim; ++cc){
    short8 CF[2][2];
    #pragma unroll
    for (int ct = 0; ct < 2; ++ct){
      int col = cc*32 + ct*16 + l15;
      #pragma unroll
      for (int ks = 0; ks < 2; ++ks)
        CF[ct][ks] = *(const short8*)&yT[col*72 + ks*32 + lg*8];
    }
    float rc[2] = { rs[cc*32 + l15], rs[cc*32 + 16 + l15] };
    #pragma unroll
    for (int q = 0; q < 4; ++q){
      if (cc > ccmax[q]) continue;
      f32x4 acc[2];
      #pragma unroll
      for (int ct = 0; ct < 2; ++ct) acc[ct] = (f32x4){0.f,0.f,0.f,0.f};
      #pragma unroll
      for (int ks = 0; ks < 2; ++ks)
        #pragma unroll
        for (int ct = 0; ct < 2; ++ct)
          acc[ct] = __builtin_amdgcn_mfma_f32_16x16x32_bf16(
              RF[q][ks], CF[ct][ks], acc[ct], 0, 0, 0);
      #pragma unroll
      for (int ct = 0; ct < 2; ++ct)
        #pragma unroll
        for (int r = 0; r < 4; ++r){
          float v = acc[ct][r] * rrow[q][r] * rc[ct];
          v = fminf(fmaxf(v, -1.f), 1.f);
          sg[(q*16 + lg*4 + r)*40 + ct*16 + l15] = f2bf(v);
        }
      // store this 16x32 chunk (DS pipe in-order per wave; no barrier)
      {
        int row = rtiles[q]*16 + (l >> 2);
        int col = cc*32 + (l & 3)*8;
        short8 v = *(const short8*)&sg[(q*16 + (l >> 2))*40 + (l & 3)*8];
        *(short8*)&fc[(size_t)bt*65536 + (size_t)row*256 + col] = v;
      }
    }
  }
}

// ---------------------------------------------------------------------------
// k_gemm: triangle-folded GEMM. grid 640 = 40 k-groups x 16 (m,n); each block
// runs 16 decoded k-tiles (i,jc). BM=64, BN=128, BK=64. XCD swizzle keeps a
// g's 16 mn-blocks on one XCD (B-panel L2 sharing).
// ---------------------------------------------------------------------------
__global__ __launch_bounds__(256) void k_gemm(const unsigned short* __restrict__ fc,
                                              const unsigned short* __restrict__ WTf,
                                              float* __restrict__ P){
  __shared__ unsigned short Al[64*64];
  __shared__ unsigned short Bl[128*64];
  const int bid  = blockIdx.x;
  const int wgid = (bid & 7)*80 + (bid >> 3);   // bijective (640 % 8 == 0)
  const int g    = wgid >> 4;                   // 0..39
  const int rem  = wgid & 15;
  const int n0   = (rem >> 3) * 128;
  const int m0   = (rem & 7) * 64;
  const int t    = threadIdx.x;
  const int w = t >> 6, l = t & 63, l15 = l & 15, lg = l >> 4;
  const int wr = (w >> 1) * 32;
  const int wc = (w & 1) * 64;

  f32x4 acc[2][4];
  #pragma unroll
  for (int a = 0; a < 2; ++a)
    #pragma unroll
    for (int b = 0; b < 4; ++b) acc[a][b] = (f32x4){0.f,0.f,0.f,0.f};

  for (int s2 = 0; s2 < 16; ++s2){
    int ti, tjc;
    tri_decode(g*16 + s2, ti, tjc);
    const int kk = ti*256 + tjc*64;
    #pragma unroll
    for (int i2 = 0; i2 < 2; ++i2){
      int c = i2*256 + t;
      int row = c >> 3, ch = c & 7;
      int sch = ch ^ (row & 7);
      gload_lds16(fc + (size_t)(m0+row)*65536 + kk + sch*8, &Al[c*8]);
    }
    #pragma unroll
    for (int i2 = 0; i2 < 4; ++i2){
      int c = i2*256 + t;
      int row = c >> 3, ch = c & 7;
      int sch = ch ^ (row & 7);
      gload_lds16(WTf + (size_t)(n0+row)*65536 + kk + sch*8, &Bl[c*8]);
    }
    __syncthreads();
    #pragma unroll
    for (int ks = 0; ks < 2; ++ks){
      short8 af[2], bf[4];
      #pragma unroll
      for (int rt = 0; rt < 2; ++rt){
        int row = wr + rt*16 + l15;
        int pch = (ks*4 + lg) ^ (row & 7);
        af[rt] = *(const short8*)&Al[row*64 + pch*8];
      }
      #pragma unroll
      for (int ct = 0; ct < 4; ++ct){
        int row = wc + ct*16 + l15;
        int pch = (ks*4 + lg) ^ (row & 7);
        bf[ct] = *(const short8*)&Bl[row*64 + pch*8];
      }
      #pragma unroll
      for (int rt = 0; rt < 2; ++rt)
        #pragma unroll
        for (int ct = 0; ct < 4; ++ct)
          acc[rt][ct] = __builtin_amdgcn_mfma_f32_16x16x32_bf16(
              af[rt], bf[ct], acc[rt][ct], 0, 0, 0);
    }
    __syncthreads();
  }

  float* Pb = P + (size_t)g * 131072;
  #pragma unroll
  for (int rt = 0; rt < 2; ++rt)
    #pragma unroll
    for (int ct = 0; ct < 4; ++ct)
      #pragma unroll
      for (int r = 0; r < 4; ++r){
        int row = m0 + wr + rt*16 + lg*4 + r;
        int col = n0 + wc + ct*16 + l15;
        Pb[(size_t)row*256 + col] = acc[rt][ct][r];
      }
}

// ---------------------------------------------------------------------------
// k_reduce: z1[row][j] = sum_{g<40} P[g][row][j]; fused BN1 stats partials.
// ---------------------------------------------------------------------------
__global__ __launch_bounds__(256) void k_reduce(const float* __restrict__ P,
                                                float* __restrict__ z,
                                                float2* __restrict__ SQ1){
  __shared__ float4 ex[128];
  const int t = threadIdx.x;
  const int row = blockIdx.x*2 + (t >> 7);
  const int c2  = (t & 127) * 2;
  float sx = 0.f, sy = 0.f;
  #pragma unroll 8
  for (int ks = 0; ks < 40; ++ks){
    const float* p = &P[(size_t)ks*131072 + row*256 + c2];
    sx += p[0]; sy += p[1];
  }
  z[row*256 + c2]     = sx;
  z[row*256 + c2 + 1] = sy;
  if (t >= 128) ex[t & 127] = make_float4(sx, sx*sx, sy, sy*sy);
  __syncthreads();
  if (t < 128){
    float4 o = ex[t];
    atomicAdd(&SQ1[c2].x,     sx + o.x);
    atomicAdd(&SQ1[c2].y,     sx*sx + o.y);
    atomicAdd(&SQ1[c2 + 1].x, sy + o.z);
    atomicAdd(&SQ1[c2 + 1].y, sy*sy + o.w);
  }
}

// ---------------------------------------------------------------------------
// k_sgm: weight-stationary MFMA layer. (R7/R8 verified)
// ---------------------------------------------------------------------------
template<int KK, int NC64, bool CAT>
__global__ __launch_bounds__(256) void k_sgm(const float* __restrict__ zin,
                                             const float* __restrict__ es,
                                             const unsigned short* __restrict__ WTl_g,
                                             const float2* __restrict__ SQin,
                                             const float* __restrict__ g,
                                             const float* __restrict__ be,
                                             float2* __restrict__ SQout,
                                             float* __restrict__ zout){
  constexpr int NCOLS = NC64 * 64;
  constexpr int NP = KK / 64;
  __shared__ unsigned short Bl[NP][NCOLS*64];
  __shared__ float2 ssl[256];
  const int r0 = blockIdx.x * 16;
  const int n0 = blockIdx.y * NCOLS;
  const int b  = r0 >> 6;
  const int t = threadIdx.x;
  const int l = t & 63, l15 = l & 15, lg = (l >> 4) & 3;
  const int w = t >> 6;
  const int wc = w * (NCOLS/4);

  #pragma unroll
  for (int p = 0; p < NP; ++p){
    #pragma unroll
    for (int i = 0; i < NCOLS*8/256; ++i){
      int c = i*256 + t;
      int row = c >> 3, ch = c & 7;
      int sch = ch ^ (row & 7);
      gload_lds16(WTl_g + (size_t)(n0+row)*KK + p*64 + sch*8, &Bl[p][c*8]);
    }
  }
  {
    float2 sq = SQin[t];
    float mu  = sq.x * (1.f/512.f);
    float var = sq.y * (1.f/512.f) - mu*mu;
    float sc  = g[t] * rsqrtf(var + 1e-5f);
    ssl[t] = make_float2(sc, be[t] - mu*sc);
  }
  __syncthreads();

  short8 a[KK/32];
  #pragma unroll
  for (int ks = 0; ks < KK/32; ++ks){
    int k = ks*32 + lg*8;
    short8 v;
    if (!CAT || k < 256){
      f32x4 lo = *(const f32x4*)&zin[(size_t)(r0+l15)*256 + k];
      f32x4 hi = *(const f32x4*)&zin[(size_t)(r0+l15)*256 + k + 4];
      #pragma unroll
      for (int j = 0; j < 4; ++j){
        float2 sv0 = ssl[k+j];
        float2 sv1 = ssl[k+4+j];
        v[j]   = (short)f2bf(fmaxf(lo[j]*sv0.x + sv0.y, 0.f));
        v[4+j] = (short)f2bf(fmaxf(hi[j]*sv1.x + sv1.y, 0.f));
      }
    } else {
      f32x4 lo = *(const f32x4*)&es[b*256 + (k-256)];
      f32x4 hi = *(const f32x4*)&es[b*256 + (k-256) + 4];
      #pragma unroll
      for (int j = 0; j < 4; ++j){
        v[j]   = (short)f2bf(lo[j]);
        v[4+j] = (short)f2bf(hi[j]);
      }
    }
    a[ks] = v;
  }

  f32x4 acc[NC64];
  #pragma unroll
  for (int ct = 0; ct < NC64; ++ct) acc[ct] = (f32x4){0.f,0.f,0.f,0.f};
  #pragma unroll
  for (int ks = 0; ks < KK/32; ++ks){
    int p = ks >> 1;
    int kin = (ks & 1) * 4;
    #pragma unroll
    for (int ct = 0; ct < NC64; ++ct){
      int row = wc + ct*16 + l15;
      int pch = (kin + lg) ^ (row & 7);
      short8 bfr = *(const short8*)&Bl[p][row*64 + pch*8];
      acc[ct] = __builtin_amdgcn_mfma_f32_16x16x32_bf16(a[ks], bfr, acc[ct], 0, 0, 0);
    }
  }

  #pragma unroll
  for (int ct = 0; ct < NC64; ++ct){
    int col = n0 + wc + ct*16 + l15;
    #pragma unroll
    for (int r = 0; r < 4; ++r)
      zout[(size_t)(r0 + lg*4 + r)*256 + col] = acc[ct][r];
    float S = acc[ct][0] + acc[ct][1] + acc[ct][2] + acc[ct][3];
    float Q = acc[ct][0]*acc[ct][0] + acc[ct][1]*acc[ct][1]
            + acc[ct][2]*acc[ct][2] + acc[ct][3]*acc[ct][3];
    S += __shfl_xor(S, 16); S += __shfl_xor(S, 32);
    Q += __shfl_xor(Q, 16); Q += __shfl_xor(Q, 32);
    if ((l >> 4) == 0){
      atomicAdd(&SQout[col].x, S);
      atomicAdd(&SQout[col].y, Q);
    }
  }
}

// ---------------------------------------------------------------------------
// k_qmean: per b: hm = mean_t relu(bn4(z4)); q = hm @ qW + qb.
// ---------------------------------------------------------------------------
__global__ __launch_bounds__(256) void k_qmean(const float* __restrict__ z4,
                                               const float2* __restrict__ SQ4,
                                               const float* __restrict__ g,
                                               const float* __restrict__ be,
                                               const float* __restrict__ qW,
                                               const float* __restrict__ qb,
                                               float* __restrict__ q){
  __shared__ float Wl[2][64*256];
  __shared__ float hm[256];
  const int b = blockIdx.x, t = threadIdx.x;
  float2 sq = SQ4[t];
  float mu  = sq.x * (1.f/512.f);
  float var = sq.y * (1.f/512.f) - mu*mu;
  float sc  = g[t] * rsqrtf(var + 1e-5f);
  float sh  = be[t] - mu*sc;
  float s = 0.f;
  #pragma unroll 8
  for (int tt = 0; tt < 64; ++tt)
    s += fmaxf(z4[((b<<6)+tt)*256 + t]*sc + sh, 0.f);
  hm[t] = s * (1.f/64.f);
  auto stage = [&](int bb, int c0){
    const float* Wg = qW + (size_t)c0 * 64 * 256;
    #pragma unroll
    for (int i = 0; i < 16; ++i){
      int c = i*256 + t;
      gload_lds16(Wg + c*4, &Wl[bb][c*4]);
    }
  };
  stage(0, 0);
  float a = 0.f;
  int cur = 0;
  for (int c = 0; c < 4; ++c){
    __syncthreads();
    if (c < 3) stage(cur ^ 1, c + 1);
    #pragma unroll 16
    for (int k = 0; k < 64; ++k)
      a += hm[c*64 + k] * Wl[cur][k*256 + t];
    cur ^= 1;
  }
  q[b*256 + t] = a + qb[t];
}

// ---------------------------------------------------------------------------
// k_att2: 16 rows/block; Hh = relu(bn4(z4)); kvec = Hh@kW + kb;
// s = dot(q_b,kvec)/16; out = Hh*sigmoid(s).
// ---------------------------------------------------------------------------
__global__ __launch_bounds__(256) void k_att2(const float* __restrict__ z4,
                                              const float2* __restrict__ SQ4,
                                              const float* __restrict__ g,
                                              const float* __restrict__ be,
                                              const unsigned short* __restrict__ kWT,
                                              const float* __restrict__ kb,
                                              const float* __restrict__ qv,
                                              float* __restrict__ out){
  __shared__ unsigned short Bl[4][256*64];
  __shared__ float2 ssl[256];
  __shared__ float Hh[16][260];
  __shared__ float pr[4][16];
  __shared__ float sig[16];
  const int r0 = blockIdx.x * 16;
  const int b  = r0 >> 6;
  const int t = threadIdx.x;
  const int l = t & 63, l15 = l & 15, lg = (l >> 4) & 3;
  const int w = t >> 6;
  const int wc = w * 64;

  #pragma unroll
  for (int p = 0; p < 4; ++p){
    #pragma unroll
    for (int i = 0; i < 8; ++i){
      int c = i*256 + t;
      int row = c >> 3, ch = c & 7;
      int sch = ch ^ (row & 7);
      gload_lds16(kWT + (size_t)row*256 + p*64 + sch*8, &Bl[p][c*8]);
    }
  }
  {
    float2 sq = SQ4[t];
    float mu  = sq.x * (1.f/512.f);
    float var = sq.y * (1.f/512.f) - mu*mu;
    float sc  = g[t] * rsqrtf(var + 1e-5f);
    ssl[t] = make_float2(sc, be[t] - mu*sc);
  }
  __syncthreads();

  short8 a[8];
  #pragma unroll
  for (int ks = 0; ks < 8; ++ks){
    int k = ks*32 + lg*8;
    f32x4 lo = *(const f32x4*)&z4[(size_t)(r0+l15)*256 + k];
    f32x4 hi = *(const f32x4*)&z4[(size_t)(r0+l15)*256 + k + 4];
    short8 v;
    f32x4 h0, h1;
    #pragma unroll
    for (int j = 0; j < 4; ++j){
      float2 sv0 = ssl[k+j];
      float2 sv1 = ssl[k+4+j];
      float x0 = fmaxf(lo[j]*sv0.x + sv0.y, 0.f);
      float x1 = fmaxf(hi[j]*sv1.x + sv1.y, 0.f);
      h0[j] = x0; h1[j] = x1;
      v[j]   = (short)f2bf(x0);
      v[4+j] = (short)f2bf(x1);
    }
    a[ks] = v;
    *(f32x4*)&Hh[l15][k]     = h0;
    *(f32x4*)&Hh[l15][k + 4] = h1;
  }

  f32x4 acc[4];
  #pragma unroll
  for (int ct = 0; ct < 4; ++ct) acc[ct] = (f32x4){0.f,0.f,0.f,0.f};
  #pragma unroll
  for (int ks = 0; ks < 8; ++ks){
    int p = ks >> 1;
    int kin = (ks & 1) * 4;
    #pragma unroll
    for (int ct = 0; ct < 4; ++ct){
      int row = wc + ct*16 + l15;
      int pch = (kin + lg) ^ (row & 7);
      short8 bfr = *(const short8*)&Bl[p][row*64 + pch*8];
      acc[ct] = __builtin_amdgcn_mfma_f32_16x16x32_bf16(a[ks], bfr, acc[ct], 0, 0, 0);
    }
  }

  float p4[4] = {0.f, 0.f, 0.f, 0.f};
  #pragma unroll
  for (int ct = 0; ct < 4; ++ct){
    int col = wc + ct*16 + l15;
    float qc  = qv[b*256 + col];
    float kbc = kb[col];
    #pragma unroll
    for (int r = 0; r < 4; ++r) p4[r] += (acc[ct][r] + kbc) * qc;
  }
  #pragma unroll
  for (int r = 0; r < 4; ++r){
    p4[r] += __shfl_xor(p4[r], 1);
    p4[r] += __shfl_xor(p4[r], 2);
    p4[r] += __shfl_xor(p4[r], 4);
    p4[r] += __shfl_xor(p4[r], 8);
  }
  if (l15 == 0){
    #pragma unroll
    for (int r = 0; r < 4; ++r) pr[w][lg*4 + r] = p4[r];
  }
  __syncthreads();
  if (t < 16){
    float s = pr[0][t] + pr[1][t] + pr[2][t] + pr[3][t];
    sig[t] = 1.f / (1.f + __expf(-s * (1.f/16.f)));
  }
  __syncthreads();
  #pragma unroll
  for (int r = 0; r < 16; ++r)
    out[(size_t)(r0+r)*256 + t] = Hh[r][t] * sig[r];
}

// ---------------------------------------------------------------------------
extern "C" void kernel_launch(void* const* d_in, const int* in_sizes, int n_in,
                              void* d_out, int out_size, void* d_ws, size_t ws_size,
                              hipStream_t stream){
  (void)in_sizes; (void)n_in; (void)out_size; (void)ws_size;
  const float* x    = (const float*)d_in[0];
  const float* e_s  = (const float*)d_in[1];
  const float* qW   = (const float*)d_in[2];
  const float* qb   = (const float*)d_in[3];
  const float* kW   = (const float*)d_in[4];
  const float* kb   = (const float*)d_in[5];
  const float* m1W  = (const float*)d_in[6];
  const float* m1g  = (const float*)d_in[8];
  const float* m1be = (const float*)d_in[9];
  const float* m2W  = (const float*)d_in[10];
  const float* m2g  = (const float*)d_in[12];
  const float* m2be = (const float*)d_in[13];
  const float* p1W  = (const float*)d_in[14];
  const float* p1g  = (const float*)d_in[16];
  const float* p1be = (const float*)d_in[17];
  const float* p2W  = (const float*)d_in[18];
  const float* p2g  = (const float*)d_in[20];
  const float* p2be = (const float*)d_in[21];
  // biases m1b,m2b,p1b,p2b cancel in BN — unused.

  char* ws = (char*)d_ws;
  unsigned short* WTf = (unsigned short*)ws; ws += 33554432;
  unsigned short* fc  = (unsigned short*)ws; ws += 67108864;
  float* P            = (float*)ws;  ws += 33554432;   // 21MB used (40 groups)
  float* z1           = (float*)ws;  ws += 524288;
  float* z2           = (float*)ws;  ws += 524288;
  float* z3           = (float*)ws;  ws += 524288;
  float* z4           = (float*)ws;  ws += 524288;
  unsigned short* WTs = (unsigned short*)ws; ws += 655360;
  float2* SQ          = (float2*)ws; ws += 8192;   // SQ1..SQ4, 256 each
  float* qvv          = (float*)ws;  ws += 8192;
  float* out = (float*)d_out;

  const unsigned short* m2WT = WTs;
  const unsigned short* p1WT = WTs + 65536;
  const unsigned short* p2WT = WTs + 196608;
  const unsigned short* kWT  = WTs + 262144;
  float2* SQ1 = SQ, *SQ2 = SQ + 256, *SQ3 = SQ + 512, *SQ4 = SQ + 768;

  k_wtf   <<<2640, 256, 0, stream>>>(m1W, WTf, m2W, p1W, p2W, kW, WTs, SQ);
  k_corr2 <<<512, 256, 0, stream>>>(x, fc);
  k_gemm  <<<640, 256, 0, stream>>>(fc, WTf, P);
  k_reduce<<<256, 256, 0, stream>>>(P, z1, SQ1);
  k_sgm<256,4,false><<<32, 256, 0, stream>>>(z1, nullptr, m2WT, SQ1, m1g, m1be, SQ2, z2);
  k_sgm<512,2,true> <<<dim3(32,2), 256, 0, stream>>>(z2, e_s, p1WT, SQ2, m2g, m2be, SQ3, z3);
  k_sgm<256,4,false><<<32, 256, 0, stream>>>(z3, nullptr, p2WT, SQ3, p1g, p1be, SQ4, z4);
  k_qmean <<<8, 256, 0, stream>>>(z4, SQ4, p2g, p2be, qW, qb, qvv);
  k_att2  <<<32, 256, 0, stream>>>(z4, SQ4, p2g, p2be, kWT, kb, qvv, out);
}

// Round 10
// 120.799 us; speedup vs baseline: 1.6670x; 1.0517x over previous
//
#include <hip/hip_runtime.h>
#include <stdint.h>
#include <stddef.h>

// ---------------------------------------------------------------------------
// ModuleGARO. R10: (1) corr fc-stores coalesced via per-wave 16x256 LDS row
// tile (1KB contiguous stores); (2) gemm 2-phase double-buffer (loads overlap
// compute, one barrier/iter); (3) sgm NC64=1 grid(32,4) = 128 blocks;
// (4) qmean 32 blocks (8b x 4 col-quarters).
// Symmetry fold (R9): WTf[(i,j)] = W_ij+W_ji (j<i), W_ii, 0 (j>i); GEMM runs
// 640 of 1024 k-tiles. Linear biases cancel in BN.
// ---------------------------------------------------------------------------

typedef short short8 __attribute__((ext_vector_type(8)));
typedef float f32x4 __attribute__((ext_vector_type(4)));

#define DEV __device__ __forceinline__

DEV unsigned short f2bf(float f){
  union { float f; unsigned u; } v; v.f = f;
  unsigned r = v.u + 0x7FFFu + ((v.u >> 16) & 1u);   // RNE
  return (unsigned short)(r >> 16);
}
DEV float bf2f(unsigned short b){
  union { unsigned u; float f; } v; v.u = ((unsigned)b) << 16;
  return v.f;
}
DEV void gload_lds16(const void* g, void* l){
  __builtin_amdgcn_global_load_lds(
      (const __attribute__((address_space(1))) unsigned int*)g,
      (__attribute__((address_space(3))) unsigned int*)l, 16, 0, 0);
}

// decode triangle-tile index t (0..639) -> (i, jc)
DEV void tri_decode(int t, int& i, int& jc){
  int a, u;
  if (t < 64)       { a = 0; u = t; }
  else if (t < 192) { a = 1; u = t - 64; }
  else if (t < 384) { a = 2; u = t - 192; }
  else              { a = 3; u = t - 384; }
  int idx = (a == 0) ? u : (a == 1) ? (u >> 1) : (a == 2) ? (u / 3) : (u >> 2);
  jc = u - idx * (a + 1);
  i = 64*a + idx;
}

// ---------------------------------------------------------------------------
// k_wtf: blocks [0,2560) = folded transpose of m1W into WTf; blocks
// [2560,2640) = tail-weight transposes + SQ zero. (R9 verified)
// ---------------------------------------------------------------------------
__global__ __launch_bounds__(256) void k_wtf(const float* __restrict__ W,
                                             unsigned short* __restrict__ WTf,
                                             const float* __restrict__ m2W,
                                             const float* __restrict__ p1W,
                                             const float* __restrict__ p2W,
                                             const float* __restrict__ kW,
                                             unsigned short* __restrict__ WTs,
                                             float2* __restrict__ SQ){
  __shared__ float tile [64][65];
  __shared__ float tile2[64][65];
  const int tr = threadIdx.x >> 6, tc = threadIdx.x & 63;
  const int bid = blockIdx.x;

  if (bid >= 2560){
    const int sub = bid - 2560;              // 0..79
    if (sub == 0){
      for (int i = threadIdx.x; i < 1024; i += 256) SQ[i] = make_float2(0.f, 0.f);
    }
    const int bx = sub >> 2, oy = sub & 3;
    const float* Ws; int K; size_t dst; int kt;
    if (bx < 4)       { Ws = m2W; K = 256; dst = 0;      kt = bx; }
    else if (bx < 12) { Ws = p1W; K = 512; dst = 65536;  kt = bx - 4; }
    else if (bx < 16) { Ws = p2W; K = 256; dst = 196608; kt = bx - 12; }
    else              { Ws = kW;  K = 256; dst = 262144; kt = bx - 16; }
    const int k0 = kt*64, o0 = oy*64;
    #pragma unroll
    for (int q = 0; q < 16; ++q){
      int kr = q*4 + tr;
      tile[kr][tc] = Ws[(size_t)(k0+kr)*256 + o0 + tc];
    }
    __syncthreads();
    #pragma unroll
    for (int q = 0; q < 16; ++q){
      int orow = q*4 + tr;
      WTs[dst + (size_t)(o0+orow)*K + k0 + tc] = f2bf(tile[tc][orow]);
    }
    return;
  }

  int i, jc;
  tri_decode(bid >> 2, i, jc);
  const int j0 = jc * 64;
  const int o0 = (bid & 3) * 64;
  #pragma unroll
  for (int q = 0; q < 16; ++q){
    int kr = q*4 + tr;
    tile [kr][tc] = W[(size_t)(i*256 + j0 + kr)*256 + o0 + tc];     // W[(i,j)][o]
    tile2[kr][tc] = W[(size_t)((j0 + kr)*256 + i)*256 + o0 + tc];   // W[(j,i)][o]
  }
  __syncthreads();
  #pragma unroll
  for (int q = 0; q < 16; ++q){
    int orow = q*4 + tr;
    int j = j0 + tc;
    float v = (j < i) ? (tile[tc][orow] + tile2[tc][orow])
            : (j == i) ? tile[tc][orow] : 0.f;
    WTf[(size_t)(o0+orow)*65536 + (size_t)i*256 + j0 + tc] = f2bf(v);
  }
}

// ---------------------------------------------------------------------------
// k_corr2: one block per bt; lower-triangle only. Wave w owns rt-tiles
// {2w,2w+1,14-2w,15-2w}; per tile, chunks cc<=2*band+1 accumulate into a
// 16x264 LDS row-tile, then stored as contiguous rows (coalesced).
// ---------------------------------------------------------------------------
__global__ __launch_bounds__(256) void k_corr2(const float* __restrict__ x,
                                               unsigned short* __restrict__ fc){
  __shared__ unsigned short yT[256*72];
  __shared__ float rs[256];
  __shared__ unsigned short twbuf[4][16*264];
  const int bt = blockIdx.x;
  const float* xb = x + (size_t)bt * 16384;
  const int i = threadIdx.x;

  float sum = 0.f;
  #pragma unroll 8
  for (int s = 0; s < 64; ++s) sum += xb[s*256 + i];
  const float mean = sum * (1.f/64.f);

  float ss = 0.f;
  unsigned int* yT32 = (unsigned int*)yT;
  #pragma unroll 4
  for (int s = 0; s < 64; s += 2){
    float v0 = xb[s*256 + i] - mean;
    float v1 = xb[(s+1)*256 + i] - mean;
    unsigned short b0 = f2bf(v0), b1 = f2bf(v1);
    float r0 = bf2f(b0), r1 = bf2f(b1);
    ss += r0*r0 + r1*r1;
    yT32[(i*72 + s) >> 1] = (unsigned)b0 | ((unsigned)b1 << 16);
  }
  rs[i] = rsqrtf(ss);
  __syncthreads();

  const int w   = threadIdx.x >> 6;
  const int l   = threadIdx.x & 63;
  const int l15 = l & 15, lg = l >> 4;
  const int rtiles[4] = {2*w, 2*w + 1, 14 - 2*w, 15 - 2*w};
  unsigned short* tw = twbuf[w];

  for (int q = 0; q < 4; ++q){
    const int rt = rtiles[q];
    const int band = rt >> 2;
    const int ccmax = 2*band + 1;

    short8 RF[2];
    #pragma unroll
    for (int ks = 0; ks < 2; ++ks)
      RF[ks] = *(const short8*)&yT[(rt*16 + l15)*72 + ks*32 + lg*8];
    float rrow[4];
    #pragma unroll
    for (int r = 0; r < 4; ++r) rrow[r] = rs[rt*16 + lg*4 + r];

    for (int cc = 0; cc <= ccmax; ++cc){
      short8 CF[2][2];
      #pragma unroll
      for (int ct = 0; ct < 2; ++ct){
        int col = cc*32 + ct*16 + l15;
        #pragma unroll
        for (int ks = 0; ks < 2; ++ks)
          CF[ct][ks] = *(const short8*)&yT[col*72 + ks*32 + lg*8];
      }
      f32x4 acc[2];
      #pragma unroll
      for (int ct = 0; ct < 2; ++ct) acc[ct] = (f32x4){0.f,0.f,0.f,0.f};
      #pragma unroll
      for (int ks = 0; ks < 2; ++ks)
        #pragma unroll
        for (int ct = 0; ct < 2; ++ct)
          acc[ct] = __builtin_amdgcn_mfma_f32_16x16x32_bf16(
              RF[ks], CF[ct][ks], acc[ct], 0, 0, 0);
      float rc[2] = { rs[cc*32 + l15], rs[cc*32 + 16 + l15] };
      #pragma unroll
      for (int ct = 0; ct < 2; ++ct)
        #pragma unroll
        for (int r = 0; r < 4; ++r){
          float v = acc[ct][r] * rrow[r] * rc[ct];
          v = fminf(fmaxf(v, -1.f), 1.f);
          tw[(lg*4 + r)*264 + cc*32 + ct*16 + l15] = f2bf(v);
        }
    }
    // coalesced store: 16 rows x nc cols (DS in-order per wave; no barrier)
    const int nc  = (ccmax + 1) * 32;
    const int spr = nc >> 3;               // 8-elem slots per row
    const int total = spr << 4;            // 16 rows
    for (int s = l; s < total; s += 64){
      int r  = s / spr;
      int co = (s - r*spr) * 8;
      short8 v = *(const short8*)&tw[r*264 + co];
      *(short8*)&fc[(size_t)bt*65536 + (size_t)(rt*16 + r)*256 + co] = v;
    }
  }
}

// ---------------------------------------------------------------------------
// k_gemm: triangle-folded GEMM, 2-phase double-buffered LDS (48KB, 3/CU).
// grid 640 = 40 k-groups x 16 (m,n); BM=64, BN=128, BK=64; XCD swizzle.
// ---------------------------------------------------------------------------
__global__ __launch_bounds__(256) void k_gemm(const unsigned short* __restrict__ fc,
                                              const unsigned short* __restrict__ WTf,
                                              float* __restrict__ P){
  __shared__ unsigned short Al[2][64*64];
  __shared__ unsigned short Bl[2][128*64];
  const int bid  = blockIdx.x;
  const int wgid = (bid & 7)*80 + (bid >> 3);   // bijective (640 % 8 == 0)
  const int g    = wgid >> 4;
  const int rem  = wgid & 15;
  const int n0   = (rem >> 3) * 128;
  const int m0   = (rem & 7) * 64;
  const int t    = threadIdx.x;
  const int w = t >> 6, l = t & 63, l15 = l & 15, lg = l >> 4;
  const int wr = (w >> 1) * 32;
  const int wc = (w & 1) * 64;

  auto stage = [&](int bsel, int s2){
    int ti, tjc;
    tri_decode(g*16 + s2, ti, tjc);
    const int kk = ti*256 + tjc*64;
    #pragma unroll
    for (int i2 = 0; i2 < 2; ++i2){
      int c = i2*256 + t;
      int row = c >> 3, ch = c & 7;
      int sch = ch ^ (row & 7);
      gload_lds16(fc + (size_t)(m0+row)*65536 + kk + sch*8, &Al[bsel][c*8]);
    }
    #pragma unroll
    for (int i2 = 0; i2 < 4; ++i2){
      int c = i2*256 + t;
      int row = c >> 3, ch = c & 7;
      int sch = ch ^ (row & 7);
      gload_lds16(WTf + (size_t)(n0+row)*65536 + kk + sch*8, &Bl[bsel][c*8]);
    }
  };

  f32x4 acc[2][4];
  #pragma unroll
  for (int a = 0; a < 2; ++a)
    #pragma unroll
    for (int b = 0; b < 4; ++b) acc[a][b] = (f32x4){0.f,0.f,0.f,0.f};

  stage(0, 0);
  int cur = 0;
  for (int s2 = 0; s2 < 16; ++s2){
    __syncthreads();                  // buf[cur] staged (vmcnt drained)
    if (s2 < 15) stage(cur ^ 1, s2 + 1);   // next-tile loads fly under compute
    #pragma unroll
    for (int ks = 0; ks < 2; ++ks){
      short8 af[2], bf[4];
      #pragma unroll
      for (int rt = 0; rt < 2; ++rt){
        int row = wr + rt*16 + l15;
        int pch = (ks*4 + lg) ^ (row & 7);
        af[rt] = *(const short8*)&Al[cur][row*64 + pch*8];
      }
      #pragma unroll
      for (int ct = 0; ct < 4; ++ct){
        int row = wc + ct*16 + l15;
        int pch = (ks*4 + lg) ^ (row & 7);
        bf[ct] = *(const short8*)&Bl[cur][row*64 + pch*8];
      }
      #pragma unroll
      for (int rt = 0; rt < 2; ++rt)
        #pragma unroll
        for (int ct = 0; ct < 4; ++ct)
          acc[rt][ct] = __builtin_amdgcn_mfma_f32_16x16x32_bf16(
              af[rt], bf[ct], acc[rt][ct], 0, 0, 0);
    }
    cur ^= 1;
  }

  float* Pb = P + (size_t)g * 131072;
  #pragma unroll
  for (int rt = 0; rt < 2; ++rt)
    #pragma unroll
    for (int ct = 0; ct < 4; ++ct)
      #pragma unroll
      for (int r = 0; r < 4; ++r){
        int row = m0 + wr + rt*16 + lg*4 + r;
        int col = n0 + wc + ct*16 + l15;
        Pb[(size_t)row*256 + col] = acc[rt][ct][r];
      }
}

// ---------------------------------------------------------------------------
// k_reduce: z1 = sum_{g<40} P[g]; fused BN1 stats partials via atomicAdd.
// ---------------------------------------------------------------------------
__global__ __launch_bounds__(256) void k_reduce(const float* __restrict__ P,
                                                float* __restrict__ z,
                                                float2* __restrict__ SQ1){
  __shared__ float4 ex[128];
  const int t = threadIdx.x;
  const int row = blockIdx.x*2 + (t >> 7);
  const int c2  = (t & 127) * 2;
  float sx = 0.f, sy = 0.f;
  #pragma unroll 8
  for (int ks = 0; ks < 40; ++ks){
    const float* p = &P[(size_t)ks*131072 + row*256 + c2];
    sx += p[0]; sy += p[1];
  }
  z[row*256 + c2]     = sx;
  z[row*256 + c2 + 1] = sy;
  if (t >= 128) ex[t & 127] = make_float4(sx, sx*sx, sy, sy*sy);
  __syncthreads();
  if (t < 128){
    float4 o = ex[t];
    atomicAdd(&SQ1[c2].x,     sx + o.x);
    atomicAdd(&SQ1[c2].y,     sx*sx + o.y);
    atomicAdd(&SQ1[c2 + 1].x, sy + o.z);
    atomicAdd(&SQ1[c2 + 1].y, sy*sy + o.w);
  }
}

// ---------------------------------------------------------------------------
// k_sgm: weight-stationary MFMA layer. 16 rows x NCOLS cols per block.
// R10: NC64=1 (NCOLS=64), grid (32,4) = 128 blocks, 32/64KB LDS.
// ---------------------------------------------------------------------------
template<int KK, int NC64, bool CAT>
__global__ __launch_bounds__(256) void k_sgm(const float* __restrict__ zin,
                                             const float* __restrict__ es,
                                             const unsigned short* __restrict__ WTl_g,
                                             const float2* __restrict__ SQin,
                                             const float* __restrict__ g,
                                             const float* __restrict__ be,
                                             float2* __restrict__ SQout,
                                             float* __restrict__ zout){
  constexpr int NCOLS = NC64 * 64;
  constexpr int NP = KK / 64;
  __shared__ unsigned short Bl[NP][NCOLS*64];
  __shared__ float2 ssl[256];
  const int r0 = blockIdx.x * 16;
  const int n0 = blockIdx.y * NCOLS;
  const int b  = r0 >> 6;
  const int t = threadIdx.x;
  const int l = t & 63, l15 = l & 15, lg = (l >> 4) & 3;
  const int w = t >> 6;
  const int wc = w * (NCOLS/4);

  #pragma unroll
  for (int p = 0; p < NP; ++p){
    #pragma unroll
    for (int i = 0; i < NCOLS*8/256; ++i){
      int c = i*256 + t;
      int row = c >> 3, ch = c & 7;
      int sch = ch ^ (row & 7);
      gload_lds16(WTl_g + (size_t)(n0+row)*KK + p*64 + sch*8, &Bl[p][c*8]);
    }
  }
  {
    float2 sq = SQin[t];
    float mu  = sq.x * (1.f/512.f);
    float var = sq.y * (1.f/512.f) - mu*mu;
    float sc  = g[t] * rsqrtf(var + 1e-5f);
    ssl[t] = make_float2(sc, be[t] - mu*sc);
  }
  __syncthreads();

  short8 a[KK/32];
  #pragma unroll
  for (int ks = 0; ks < KK/32; ++ks){
    int k = ks*32 + lg*8;
    short8 v;
    if (!CAT || k < 256){
      f32x4 lo = *(const f32x4*)&zin[(size_t)(r0+l15)*256 + k];
      f32x4 hi = *(const f32x4*)&zin[(size_t)(r0+l15)*256 + k + 4];
      #pragma unroll
      for (int j = 0; j < 4; ++j){
        float2 sv0 = ssl[k+j];
        float2 sv1 = ssl[k+4+j];
        v[j]   = (short)f2bf(fmaxf(lo[j]*sv0.x + sv0.y, 0.f));
        v[4+j] = (short)f2bf(fmaxf(hi[j]*sv1.x + sv1.y, 0.f));
      }
    } else {
      f32x4 lo = *(const f32x4*)&es[b*256 + (k-256)];
      f32x4 hi = *(const f32x4*)&es[b*256 + (k-256) + 4];
      #pragma unroll
      for (int j = 0; j < 4; ++j){
        v[j]   = (short)f2bf(lo[j]);
        v[4+j] = (short)f2bf(hi[j]);
      }
    }
    a[ks] = v;
  }

  f32x4 acc[NC64];
  #pragma unroll
  for (int ct = 0; ct < NC64; ++ct) acc[ct] = (f32x4){0.f,0.f,0.f,0.f};
  #pragma unroll
  for (int ks = 0; ks < KK/32; ++ks){
    int p = ks >> 1;
    int kin = (ks & 1) * 4;
    #pragma unroll
    for (int ct = 0; ct < NC64; ++ct){
      int row = wc + ct*16 + l15;
      int pch = (kin + lg) ^ (row & 7);
      short8 bfr = *(const short8*)&Bl[p][row*64 + pch*8];
      acc[ct] = __builtin_amdgcn_mfma_f32_16x16x32_bf16(a[ks], bfr, acc[ct], 0, 0, 0);
    }
  }

  #pragma unroll
  for (int ct = 0; ct < NC64; ++ct){
    int col = n0 + wc + ct*16 + l15;
    #pragma unroll
    for (int r = 0; r < 4; ++r)
      zout[(size_t)(r0 + lg*4 + r)*256 + col] = acc[ct][r];
    float S = acc[ct][0] + acc[ct][1] + acc[ct][2] + acc[ct][3];
    float Q = acc[ct][0]*acc[ct][0] + acc[ct][1]*acc[ct][1]
            + acc[ct][2]*acc[ct][2] + acc[ct][3]*acc[ct][3];
    S += __shfl_xor(S, 16); S += __shfl_xor(S, 32);
    Q += __shfl_xor(Q, 16); Q += __shfl_xor(Q, 32);
    if ((l >> 4) == 0){
      atomicAdd(&SQout[col].x, S);
      atomicAdd(&SQout[col].y, Q);
    }
  }
}

// ---------------------------------------------------------------------------
// k_qmean2: 32 blocks = (8 b) x (4 col-quarters). Per block: hm = mean_t
// relu(bn4(z4[b])); q[b][n0..n0+64) = hm @ qW-slice + qb. Slice in LDS.
// ---------------------------------------------------------------------------
__global__ __launch_bounds__(256) void k_qmean2(const float* __restrict__ z4,
                                                const float2* __restrict__ SQ4,
                                                const float* __restrict__ g,
                                                const float* __restrict__ be,
                                                const float* __restrict__ qW,
                                                const float* __restrict__ qb,
                                                float* __restrict__ q){
  __shared__ float qWl[256*64];    // 64KB: qW[:, n0..n0+64) packed [k][c]
  __shared__ float hm[256];
  __shared__ float part[4][64];
  const int b  = blockIdx.x & 7;
  const int n0 = (blockIdx.x >> 3) * 64;
  const int t  = threadIdx.x;

  #pragma unroll
  for (int it = 0; it < 16; ++it){
    int s4 = it*256 + t;           // 16B-slot index
    int k  = s4 >> 4;
    int c  = (s4 & 15) * 4;
    gload_lds16(qW + (size_t)k*256 + n0 + c, (char*)qWl + (size_t)s4*16);
  }
  {
    float2 sq = SQ4[t];
    float mu  = sq.x * (1.f/512.f);
    float var = sq.y * (1.f/512.f) - mu*mu;
    float sc  = g[t] * rsqrtf(var + 1e-5f);
    float sh  = be[t] - mu*sc;
    float s = 0.f;
    #pragma unroll 8
    for (int tt = 0; tt < 64; ++tt)
      s += fmaxf(z4[(size_t)((b<<6)+tt)*256 + t]*sc + sh, 0.f);
    hm[t] = s * (1.f/64.f);
  }
  __syncthreads();                 // drains qW gloads + hm visible

  const int col = t & 63, kq = t >> 6;
  float a = 0.f;
  #pragma unroll 8
  for (int k2 = 0; k2 < 64; ++k2){
    int k = kq*64 + k2;
    a += hm[k] * qWl[k*64 + col];
  }
  part[kq][col] = a;
  __syncthreads();
  if (t < 64)
    q[b*256 + n0 + t] = part[0][t] + part[1][t] + part[2][t] + part[3][t] + qb[n0 + t];
}

// ---------------------------------------------------------------------------
// k_att2: 16 rows/block; Hh = relu(bn4(z4)); kvec = Hh@kW + kb;
// s = dot(q_b,kvec)/16; out = Hh*sigmoid(s). (R7-R9 verified)
// ---------------------------------------------------------------------------
__global__ __launch_bounds__(256) void k_att2(const float* __restrict__ z4,
                                              const float2* __restrict__ SQ4,
                                              const float* __restrict__ g,
                                              const float* __restrict__ be,
                                              const unsigned short* __restrict__ kWT,
                                              const float* __restrict__ kb,
                                              const float* __restrict__ qv,
                                              float* __restrict__ out){
  __shared__ unsigned short Bl[4][256*64];
  __shared__ float2 ssl[256];
  __shared__ float Hh[16][260];
  __shared__ float pr[4][16];
  __shared__ float sig[16];
  const int r0 = blockIdx.x * 16;
  const int b  = r0 >> 6;
  const int t = threadIdx.x;
  const int l = t & 63, l15 = l & 15, lg = (l >> 4) & 3;
  const int w = t >> 6;
  const int wc = w * 64;

  #pragma unroll
  for (int p = 0; p < 4; ++p){
    #pragma unroll
    for (int i = 0; i < 8; ++i){
      int c = i*256 + t;
      int row = c >> 3, ch = c & 7;
      int sch = ch ^ (row & 7);
      gload_lds16(kWT + (size_t)row*256 + p*64 + sch*8, &Bl[p][c*8]);
    }
  }
  {
    float2 sq = SQ4[t];
    float mu  = sq.x * (1.f/512.f);
    float var = sq.y * (1.f/512.f) - mu*mu;
    float sc  = g[t] * rsqrtf(var + 1e-5f);
    ssl[t] = make_float2(sc, be[t] - mu*sc);
  }
  __syncthreads();

  short8 a[8];
  #pragma unroll
  for (int ks = 0; ks < 8; ++ks){
    int k = ks*32 + lg*8;
    f32x4 lo = *(const f32x4*)&z4[(size_t)(r0+l15)*256 + k];
    f32x4 hi = *(const f32x4*)&z4[(size_t)(r0+l15)*256 + k + 4];
    short8 v;
    f32x4 h0, h1;
    #pragma unroll
    for (int j = 0; j < 4; ++j){
      float2 sv0 = ssl[k+j];
      float2 sv1 = ssl[k+4+j];
      float x0 = fmaxf(lo[j]*sv0.x + sv0.y, 0.f);
      float x1 = fmaxf(hi[j]*sv1.x + sv1.y, 0.f);
      h0[j] = x0; h1[j] = x1;
      v[j]   = (short)f2bf(x0);
      v[4+j] = (short)f2bf(x1);
    }
    a[ks] = v;
    *(f32x4*)&Hh[l15][k]     = h0;
    *(f32x4*)&Hh[l15][k + 4] = h1;
  }

  f32x4 acc[4];
  #pragma unroll
  for (int ct = 0; ct < 4; ++ct) acc[ct] = (f32x4){0.f,0.f,0.f,0.f};
  #pragma unroll
  for (int ks = 0; ks < 8; ++ks){
    int p = ks >> 1;
    int kin = (ks & 1) * 4;
    #pragma unroll
    for (int ct = 0; ct < 4; ++ct){
      int row = wc + ct*16 + l15;
      int pch = (kin + lg) ^ (row & 7);
      short8 bfr = *(const short8*)&Bl[p][row*64 + pch*8];
      acc[ct] = __builtin_amdgcn_mfma_f32_16x16x32_bf16(a[ks], bfr, acc[ct], 0, 0, 0);
    }
  }

  float p4[4] = {0.f, 0.f, 0.f, 0.f};
  #pragma unroll
  for (int ct = 0; ct < 4; ++ct){
    int col = wc + ct*16 + l15;
    float qc  = qv[b*256 + col];
    float kbc = kb[col];
    #pragma unroll
    for (int r = 0; r < 4; ++r) p4[r] += (acc[ct][r] + kbc) * qc;
  }
  #pragma unroll
  for (int r = 0; r < 4; ++r){
    p4[r] += __shfl_xor(p4[r], 1);
    p4[r] += __shfl_xor(p4[r], 2);
    p4[r] += __shfl_xor(p4[r], 4);
    p4[r] += __shfl_xor(p4[r], 8);
  }
  if (l15 == 0){
    #pragma unroll
    for (int r = 0; r < 4; ++r) pr[w][lg*4 + r] = p4[r];
  }
  __syncthreads();
  if (t < 16){
    float s = pr[0][t] + pr[1][t] + pr[2][t] + pr[3][t];
    sig[t] = 1.f / (1.f + __expf(-s * (1.f/16.f)));
  }
  __syncthreads();
  #pragma unroll
  for (int r = 0; r < 16; ++r)
    out[(size_t)(r0+r)*256 + t] = Hh[r][t] * sig[r];
}

// ---------------------------------------------------------------------------
extern "C" void kernel_launch(void* const* d_in, const int* in_sizes, int n_in,
                              void* d_out, int out_size, void* d_ws, size_t ws_size,
                              hipStream_t stream){
  (void)in_sizes; (void)n_in; (void)out_size; (void)ws_size;
  const float* x    = (const float*)d_in[0];
  const float* e_s  = (const float*)d_in[1];
  const float* qW   = (const float*)d_in[2];
  const float* qb   = (const float*)d_in[3];
  const float* kW   = (const float*)d_in[4];
  const float* kb   = (const float*)d_in[5];
  const float* m1W  = (const float*)d_in[6];
  const float* m1g  = (const float*)d_in[8];
  const float* m1be = (const float*)d_in[9];
  const float* m2W  = (const float*)d_in[10];
  const float* m2g  = (const float*)d_in[12];
  const float* m2be = (const float*)d_in[13];
  const float* p1W  = (const float*)d_in[14];
  const float* p1g  = (const float*)d_in[16];
  const float* p1be = (const float*)d_in[17];
  const float* p2W  = (const float*)d_in[18];
  const float* p2g  = (const float*)d_in[20];
  const float* p2be = (const float*)d_in[21];
  // biases m1b,m2b,p1b,p2b cancel in BN — unused.

  char* ws = (char*)d_ws;
  unsigned short* WTf = (unsigned short*)ws; ws += 33554432;
  unsigned short* fc  = (unsigned short*)ws; ws += 67108864;
  float* P            = (float*)ws;  ws += 33554432;   // 21MB used (40 groups)
  float* z1           = (float*)ws;  ws += 524288;
  float* z2           = (float*)ws;  ws += 524288;
  float* z3           = (float*)ws;  ws += 524288;
  float* z4           = (float*)ws;  ws += 524288;
  unsigned short* WTs = (unsigned short*)ws; ws += 655360;
  float2* SQ          = (float2*)ws; ws += 8192;   // SQ1..SQ4, 256 each
  float* qvv          = (float*)ws;  ws += 8192;
  float* out = (float*)d_out;

  const unsigned short* m2WT = WTs;
  const unsigned short* p1WT = WTs + 65536;
  const unsigned short* p2WT = WTs + 196608;
  const unsigned short* kWT  = WTs + 262144;
  float2* SQ1 = SQ, *SQ2 = SQ + 256, *SQ3 = SQ + 512, *SQ4 = SQ + 768;

  k_wtf   <<<2640, 256, 0, stream>>>(m1W, WTf, m2W, p1W, p2W, kW, WTs, SQ);
  k_corr2 <<<512, 256, 0, stream>>>(x, fc);
  k_gemm  <<<640, 256, 0, stream>>>(fc, WTf, P);
  k_reduce<<<256, 256, 0, stream>>>(P, z1, SQ1);
  k_sgm<256,1,false><<<dim3(32,4), 256, 0, stream>>>(z1, nullptr, m2WT, SQ1, m1g, m1be, SQ2, z2);
  k_sgm<512,1,true> <<<dim3(32,4), 256, 0, stream>>>(z2, e_s, p1WT, SQ2, m2g, m2be, SQ3, z3);
  k_sgm<256,1,false><<<dim3(32,4), 256, 0, stream>>>(z3, nullptr, p2WT, SQ3, p1g, p1be, SQ4, z4);
  k_qmean2<<<32, 256, 0, stream>>>(z4, SQ4, p2g, p2be, qW, qb, qvv);
  k_att2  <<<32, 256, 0, stream>>>(z4, SQ4, p2g, p2be, kWT, kb, qvv, out);
}